// Round 1
// baseline (10868.506 us; speedup 1.0000x reference)
//
#include <hip/hip_runtime.h>
#include <math.h>

// ---- problem constants ----
constexpr int BATCH   = 2;
constexpr int DIM     = 320;
constexpr int NHEADS  = 8;
constexpr int DH      = 40;      // head dim
constexpr int NGROUPS = 32;
constexpr int CPG     = 10;      // channels per group
constexpr int SPATIAL = 4096;    // 64*64
constexpr int ROWS    = BATCH * SPATIAL;  // 8192
constexpr int KVL     = 77;
constexpr int KVD     = 768;
constexpr int FF      = 1280;    // geglu half width (fc0 out = 2560)

// ---------------------------------------------------------------------------
// GroupNorm stats: one block per (b, group). Group = 10 channels x 4096 spatial.
// ---------------------------------------------------------------------------
__global__ __launch_bounds__(256) void gn_stats_kernel(const float* __restrict__ q,
                                                       float* __restrict__ stats) {
    int bg = blockIdx.x;                    // 0..63
    int b = bg / NGROUPS, g = bg % NGROUPS;
    const float* base = q + ((size_t)b * DIM + (size_t)g * CPG) * SPATIAL;
    const int n = CPG * SPATIAL;            // 40960 contiguous floats
    float s = 0.f, ss = 0.f;
    for (int i = threadIdx.x; i < n; i += 256) {
        float v = base[i];
        s += v; ss += v * v;
    }
    __shared__ float rs[256], rss[256];
    rs[threadIdx.x] = s; rss[threadIdx.x] = ss;
    __syncthreads();
    for (int off = 128; off > 0; off >>= 1) {
        if (threadIdx.x < off) {
            rs[threadIdx.x]  += rs[threadIdx.x + off];
            rss[threadIdx.x] += rss[threadIdx.x + off];
        }
        __syncthreads();
    }
    if (threadIdx.x == 0) {
        float mean = rs[0] / (float)n;
        float var  = rss[0] / (float)n - mean * mean;
        stats[bg * 2]     = mean;
        stats[bg * 2 + 1] = rsqrtf(var + 1e-6f);
    }
}

// ---------------------------------------------------------------------------
// Apply GN + transpose NCHW -> (b, l, c) token layout. 32x32 LDS tile.
// grid: (128 l-tiles, 10 c-tiles, 2 batches), block (32,32)
// ---------------------------------------------------------------------------
__global__ void gn_apply_transpose_kernel(const float* __restrict__ q,
                                          const float* __restrict__ stats,
                                          const float* __restrict__ gs,
                                          const float* __restrict__ gb,
                                          float* __restrict__ out) {
    __shared__ float tile[32][33];
    int l0 = blockIdx.x * 32, c0 = blockIdx.y * 32, b = blockIdx.z;
    int tx = threadIdx.x, ty = threadIdx.y;
    int c = c0 + ty;
    int g = c / CPG;
    float mean = stats[(b * NGROUPS + g) * 2];
    float rstd = stats[(b * NGROUPS + g) * 2 + 1];
    float v = q[((size_t)(b * DIM + c)) * SPATIAL + l0 + tx];
    tile[ty][tx] = (v - mean) * rstd * gs[c] + gb[c];
    __syncthreads();
    out[((size_t)(b * SPATIAL + l0 + ty)) * DIM + c0 + tx] = tile[tx][ty];
}

// ---------------------------------------------------------------------------
// Final: token layout -> NCHW, + residual q. out[b][c][l] = x[b][l][c] + q[b][c][l]
// ---------------------------------------------------------------------------
__global__ void out_transpose_kernel(const float* __restrict__ xin,
                                     const float* __restrict__ q,
                                     float* __restrict__ out) {
    __shared__ float tile[32][33];
    int l0 = blockIdx.x * 32, c0 = blockIdx.y * 32, b = blockIdx.z;
    int tx = threadIdx.x, ty = threadIdx.y;
    tile[ty][tx] = xin[((size_t)(b * SPATIAL + l0 + ty)) * DIM + c0 + tx];
    __syncthreads();
    size_t oi = ((size_t)(b * DIM + c0 + ty)) * SPATIAL + l0 + tx;
    out[oi] = tile[tx][ty] + q[oi];
}

// ---------------------------------------------------------------------------
// LayerNorm over rows of 320. One wave (64 threads) per row, 5 elems/thread.
// ---------------------------------------------------------------------------
__global__ __launch_bounds__(64) void ln_kernel(const float* __restrict__ x,
                                                const float* __restrict__ sc,
                                                const float* __restrict__ bi,
                                                float* __restrict__ out) {
    int row = blockIdx.x;
    const float* xr = x + (size_t)row * DIM;
    float v[5];
    float sum = 0.f, sq = 0.f;
#pragma unroll
    for (int j = 0; j < 5; j++) {
        v[j] = xr[threadIdx.x + j * 64];
        sum += v[j]; sq += v[j] * v[j];
    }
#pragma unroll
    for (int off = 32; off > 0; off >>= 1) {
        sum += __shfl_down(sum, off);
        sq  += __shfl_down(sq, off);
    }
    sum = __shfl(sum, 0); sq = __shfl(sq, 0);
    float mean = sum / (float)DIM;
    float rstd = rsqrtf(sq / (float)DIM - mean * mean + 1e-5f);
#pragma unroll
    for (int j = 0; j < 5; j++) {
        int i = threadIdx.x + j * 64;
        out[(size_t)row * DIM + i] = (v[j] - mean) * rstd * sc[i] + bi[i];
    }
}

// ---------------------------------------------------------------------------
// Generic fp32 GEMM: C[M,N] = A[M,K] @ W[K,N] (+bias) (+resid)
// 64x64 tile, BK=16, 256 threads, 4x4 micro-tile. N must be multiple of 64,
// K multiple of 16 (all call sites satisfy this). M guarded.
// ---------------------------------------------------------------------------
__global__ __launch_bounds__(256) void gemm_kernel(const float* __restrict__ A,
                                                   const float* __restrict__ W,
                                                   const float* __restrict__ bias,
                                                   const float* __restrict__ resid,
                                                   float* __restrict__ C,
                                                   int M, int N, int K) {
    __shared__ float As[16][65];
    __shared__ float Bs[16][65];
    int tid = threadIdx.x;
    int tx = tid & 15, ty = tid >> 4;
    int m0 = blockIdx.x * 64, n0 = blockIdx.y * 64;
    float acc[4][4] = {};
    for (int k0 = 0; k0 < K; k0 += 16) {
#pragma unroll
        for (int p = 0; p < 4; p++) {
            int lin = p * 256 + tid;
            int r = lin >> 4, cc = lin & 15;
            int m = m0 + r;
            As[cc][r] = (m < M) ? A[(size_t)m * K + k0 + cc] : 0.f;
        }
#pragma unroll
        for (int p = 0; p < 4; p++) {
            int lin = p * 256 + tid;
            int r = lin >> 6, cc = lin & 63;
            Bs[r][cc] = W[(size_t)(k0 + r) * N + n0 + cc];
        }
        __syncthreads();
#pragma unroll
        for (int kk = 0; kk < 16; kk++) {
            float a[4], bv[4];
#pragma unroll
            for (int i = 0; i < 4; i++) a[i] = As[kk][ty * 4 + i];
#pragma unroll
            for (int j = 0; j < 4; j++) bv[j] = Bs[kk][tx * 4 + j];
#pragma unroll
            for (int i = 0; i < 4; i++)
#pragma unroll
                for (int j = 0; j < 4; j++)
                    acc[i][j] += a[i] * bv[j];
        }
        __syncthreads();
    }
#pragma unroll
    for (int i = 0; i < 4; i++) {
        int m = m0 + ty * 4 + i;
        if (m >= M) continue;
#pragma unroll
        for (int j = 0; j < 4; j++) {
            int n = n0 + tx * 4 + j;
            float v = acc[i][j];
            if (bias)  v += bias[n];
            if (resid) v += resid[(size_t)m * N + n];
            C[(size_t)m * N + n] = v;
        }
    }
}

// ---------------------------------------------------------------------------
// fc0 + GEGLU fused: GG[m,n] = (A@W[:,n]+b[n]) * gelu(A@W[:,n+FF]+b[n+FF])
// W is [K, 2*FF]. Output [M, FF]. M, FF multiples of 64; exact erf GELU.
// ---------------------------------------------------------------------------
__global__ __launch_bounds__(256) void gemm_geglu_kernel(const float* __restrict__ A,
                                                         const float* __restrict__ W,
                                                         const float* __restrict__ bias,
                                                         float* __restrict__ C,
                                                         int M, int K) {
    const int NW = 2 * FF;
    __shared__ float As[16][65];
    __shared__ float Bv[16][65];
    __shared__ float Bg[16][65];
    int tid = threadIdx.x;
    int tx = tid & 15, ty = tid >> 4;
    int m0 = blockIdx.x * 64, n0 = blockIdx.y * 64;
    float av[4][4] = {}, ag[4][4] = {};
    for (int k0 = 0; k0 < K; k0 += 16) {
#pragma unroll
        for (int p = 0; p < 4; p++) {
            int lin = p * 256 + tid;
            int r = lin >> 4, cc = lin & 15;
            As[cc][r] = A[(size_t)(m0 + r) * K + k0 + cc];
        }
#pragma unroll
        for (int p = 0; p < 4; p++) {
            int lin = p * 256 + tid;
            int r = lin >> 6, cc = lin & 63;
            Bv[r][cc] = W[(size_t)(k0 + r) * NW + n0 + cc];
            Bg[r][cc] = W[(size_t)(k0 + r) * NW + FF + n0 + cc];
        }
        __syncthreads();
#pragma unroll
        for (int kk = 0; kk < 16; kk++) {
            float a[4], bv[4], bg[4];
#pragma unroll
            for (int i = 0; i < 4; i++) a[i] = As[kk][ty * 4 + i];
#pragma unroll
            for (int j = 0; j < 4; j++) { bv[j] = Bv[kk][tx * 4 + j]; bg[j] = Bg[kk][tx * 4 + j]; }
#pragma unroll
            for (int i = 0; i < 4; i++)
#pragma unroll
                for (int j = 0; j < 4; j++) {
                    av[i][j] += a[i] * bv[j];
                    ag[i][j] += a[i] * bg[j];
                }
        }
        __syncthreads();
    }
#pragma unroll
    for (int i = 0; i < 4; i++) {
        int m = m0 + ty * 4 + i;
#pragma unroll
        for (int j = 0; j < 4; j++) {
            int n = n0 + tx * 4 + j;
            float val  = av[i][j] + bias[n];
            float gate = ag[i][j] + bias[n + FF];
            float g = 0.5f * gate * (1.f + erff(gate * 0.70710678118654752f));
            C[(size_t)m * FF + n] = val * g;
        }
    }
}

// ---------------------------------------------------------------------------
// Attention: one block per (q_row, head, batch). Q,K,V in token layout
// [rows, 320] with head h owning columns [h*40, h*40+40). nk = keys per batch.
// ---------------------------------------------------------------------------
__global__ __launch_bounds__(256) void attn_kernel(const float* __restrict__ Q,
                                                   const float* __restrict__ Kp,
                                                   const float* __restrict__ Vp,
                                                   float* __restrict__ O,
                                                   int nk) {
    int qi = blockIdx.x, h = blockIdx.y, b = blockIdx.z;
    int tid = threadIdx.x;
    __shared__ float qv[DH];
    __shared__ float s[SPATIAL];
    __shared__ float red[256];
    __shared__ float part[256][DH];

    const float* qrow = Q + ((size_t)(b * SPATIAL + qi)) * DIM + h * DH;
    if (tid < DH) qv[tid] = qrow[tid];
    __syncthreads();

    const float scale = 0.15811388300841897f;  // 1/sqrt(40)
    const float* Kb = Kp + (size_t)b * nk * DIM + h * DH;
    for (int j = tid; j < nk; j += 256) {
        const float* kr = Kb + (size_t)j * DIM;
        float d = 0.f;
#pragma unroll
        for (int t = 0; t < DH; t++) d += qv[t] * kr[t];
        s[j] = d * scale;
    }
    __syncthreads();

    // max
    float m = -1e30f;
    for (int j = tid; j < nk; j += 256) m = fmaxf(m, s[j]);
    red[tid] = m; __syncthreads();
    for (int off = 128; off > 0; off >>= 1) {
        if (tid < off) red[tid] = fmaxf(red[tid], red[tid + off]);
        __syncthreads();
    }
    m = red[0];
    __syncthreads();

    // exp + sum
    float lsum = 0.f;
    for (int j = tid; j < nk; j += 256) {
        float e = expf(s[j] - m);
        s[j] = e;
        lsum += e;
    }
    red[tid] = lsum; __syncthreads();
    for (int off = 128; off > 0; off >>= 1) {
        if (tid < off) red[tid] += red[tid + off];
        __syncthreads();
    }
    float inv = 1.f / red[0];

    // PV: each thread a contiguous chunk of keys, acc in regs, tree-reduce
    float acc[DH];
#pragma unroll
    for (int t = 0; t < DH; t++) acc[t] = 0.f;
    int chunk = (nk + 255) / 256;
    int j0 = tid * chunk, j1 = min(nk, j0 + chunk);
    const float* Vb = Vp + (size_t)b * nk * DIM + h * DH;
    for (int j = j0; j < j1; j++) {
        float p = s[j];
        const float* vr = Vb + (size_t)j * DIM;
#pragma unroll
        for (int t = 0; t < DH; t++) acc[t] += p * vr[t];
    }
#pragma unroll
    for (int t = 0; t < DH; t++) part[tid][t] = acc[t];
    __syncthreads();
    for (int off = 128; off > 0; off >>= 1) {
        if (tid < off)
            for (int t = 0; t < DH; t++) part[tid][t] += part[tid + off][t];
        __syncthreads();
    }
    if (tid < DH)
        O[((size_t)(b * SPATIAL + qi)) * DIM + h * DH + tid] = part[0][tid] * inv;
}

// ---------------------------------------------------------------------------
extern "C" void kernel_launch(void* const* d_in, const int* in_sizes, int n_in,
                              void* d_out, int out_size, void* d_ws, size_t ws_size,
                              hipStream_t stream) {
    (void)in_sizes; (void)n_in; (void)out_size; (void)ws_size;
    const float* q      = (const float*)d_in[0];
    const float* kv     = (const float*)d_in[1];
    const float* gn_s   = (const float*)d_in[2];
    const float* gn_b   = (const float*)d_in[3];
    const float* cin_w  = (const float*)d_in[4];
    const float* cin_b  = (const float*)d_in[5];
    const float* ln0_s  = (const float*)d_in[6];
    const float* ln0_b  = (const float*)d_in[7];
    const float* a1_wq  = (const float*)d_in[8];
    const float* a1_wk  = (const float*)d_in[9];
    const float* a1_wv  = (const float*)d_in[10];
    const float* a1_wo  = (const float*)d_in[11];
    const float* a1_bo  = (const float*)d_in[12];
    const float* ln1_s  = (const float*)d_in[13];
    const float* ln1_b  = (const float*)d_in[14];
    const float* a2_wq  = (const float*)d_in[15];
    const float* a2_wk  = (const float*)d_in[16];
    const float* a2_wv  = (const float*)d_in[17];
    const float* a2_wo  = (const float*)d_in[18];
    const float* a2_bo  = (const float*)d_in[19];
    const float* lnA_s  = (const float*)d_in[20];
    const float* lnA_b  = (const float*)d_in[21];
    const float* fc0_w  = (const float*)d_in[22];
    const float* fc0_b  = (const float*)d_in[23];
    const float* fc1_w  = (const float*)d_in[24];
    const float* fc1_b  = (const float*)d_in[25];
    const float* cout_w = (const float*)d_in[26];
    const float* cout_b = (const float*)d_in[27];
    float* out = (float*)d_out;

    float* ws = (float*)d_ws;
    const size_t BS = (size_t)ROWS * DIM;        // 2,621,440 floats
    float* stats = ws;                            // 128 floats
    float* B0 = ws + 256;                         // x
    float* B1 = B0 + BS;                          // temps (gnout/xn/attnout)
    float* B2 = B1 + BS;                          // Q
    float* B3 = B2 + BS;                          // K (self)
    float* B4 = B3 + BS;                          // V (self)
    float* KK  = B4 + BS;                         // cross K [154,320]
    float* KV_ = KK + (size_t)2 * KVL * DIM;      // cross V [154,320]
    float* GG  = KV_ + (size_t)2 * KVL * DIM;     // geglu out [8192,1280]

    auto gemm = [&](const float* A, const float* W, const float* bias,
                    const float* resid, float* C, int M, int N, int K) {
        gemm_kernel<<<dim3((M + 63) / 64, N / 64), 256, 0, stream>>>(A, W, bias, resid, C, M, N, K);
    };

    // GroupNorm + transpose to tokens
    gn_stats_kernel<<<64, 256, 0, stream>>>(q, stats);
    gn_apply_transpose_kernel<<<dim3(SPATIAL / 32, DIM / 32, BATCH), dim3(32, 32), 0, stream>>>(
        q, stats, gn_s, gn_b, B1);
    // conv_in (1x1): X = GN(q) @ cin_w + cin_b
    gemm(B1, cin_w, cin_b, nullptr, B0, ROWS, DIM, DIM);

    // self-attention
    ln_kernel<<<ROWS, 64, 0, stream>>>(B0, ln0_s, ln0_b, B1);
    gemm(B1, a1_wq, nullptr, nullptr, B2, ROWS, DIM, DIM);
    gemm(B1, a1_wk, nullptr, nullptr, B3, ROWS, DIM, DIM);
    gemm(B1, a1_wv, nullptr, nullptr, B4, ROWS, DIM, DIM);
    attn_kernel<<<dim3(SPATIAL, NHEADS, BATCH), 256, 0, stream>>>(B2, B3, B4, B1, SPATIAL);
    gemm(B1, a1_wo, a1_bo, B0, B0, ROWS, DIM, DIM);   // + residual, in-place safe (elementwise)

    // cross-attention
    ln_kernel<<<ROWS, 64, 0, stream>>>(B0, ln1_s, ln1_b, B1);
    gemm(B1, a2_wq, nullptr, nullptr, B2, ROWS, DIM, DIM);
    gemm(kv, a2_wk, nullptr, nullptr, KK,  BATCH * KVL, DIM, KVD);
    gemm(kv, a2_wv, nullptr, nullptr, KV_, BATCH * KVL, DIM, KVD);
    attn_kernel<<<dim3(SPATIAL, NHEADS, BATCH), 256, 0, stream>>>(B2, KK, KV_, B1, KVL);
    gemm(B1, a2_wo, a2_bo, B0, B0, ROWS, DIM, DIM);

    // FFN (GEGLU)
    ln_kernel<<<ROWS, 64, 0, stream>>>(B0, lnA_s, lnA_b, B1);
    gemm_geglu_kernel<<<dim3(ROWS / 64, FF / 64), 256, 0, stream>>>(B1, fc0_w, fc0_b, GG, ROWS, DIM);
    gemm(GG, fc1_w, fc1_b, B0, B1, ROWS, DIM, FF);

    // conv_out (1x1) + res1, back to NCHW
    gemm(B1, cout_w, cout_b, nullptr, B2, ROWS, DIM, DIM);
    out_transpose_kernel<<<dim3(SPATIAL / 32, DIM / 32, BATCH), dim3(32, 32), 0, stream>>>(B2, q, out);
}

// Round 2
// 2508.408 us; speedup vs baseline: 4.3328x; 4.3328x over previous
//
#include <hip/hip_runtime.h>
#include <math.h>

// ---- problem constants ----
constexpr int BATCH   = 2;
constexpr int DIM     = 320;
constexpr int NHEADS  = 8;
constexpr int DH      = 40;      // head dim
constexpr int NGROUPS = 32;
constexpr int CPG     = 10;      // channels per group
constexpr int SPATIAL = 4096;    // 64*64
constexpr int ROWS    = BATCH * SPATIAL;  // 8192
constexpr int KVL     = 77;
constexpr int KVD     = 768;
constexpr int FF      = 1280;    // geglu half width (fc0 out = 2560)

// ---------------------------------------------------------------------------
// GroupNorm stats: one block per (b, group).
// ---------------------------------------------------------------------------
__global__ __launch_bounds__(256) void gn_stats_kernel(const float* __restrict__ q,
                                                       float* __restrict__ stats) {
    int bg = blockIdx.x;
    int b = bg / NGROUPS, g = bg % NGROUPS;
    const float* base = q + ((size_t)b * DIM + (size_t)g * CPG) * SPATIAL;
    const int n = CPG * SPATIAL;
    float s = 0.f, ss = 0.f;
    for (int i = threadIdx.x; i < n; i += 256) {
        float v = base[i];
        s += v; ss += v * v;
    }
    __shared__ float rs[256], rss[256];
    rs[threadIdx.x] = s; rss[threadIdx.x] = ss;
    __syncthreads();
    for (int off = 128; off > 0; off >>= 1) {
        if (threadIdx.x < off) {
            rs[threadIdx.x]  += rs[threadIdx.x + off];
            rss[threadIdx.x] += rss[threadIdx.x + off];
        }
        __syncthreads();
    }
    if (threadIdx.x == 0) {
        float mean = rs[0] / (float)n;
        float var  = rss[0] / (float)n - mean * mean;
        stats[bg * 2]     = mean;
        stats[bg * 2 + 1] = rsqrtf(var + 1e-6f);
    }
}

// ---------------------------------------------------------------------------
// Apply GN + transpose NCHW -> (b, l, c). 32x32 LDS tile.
// ---------------------------------------------------------------------------
__global__ void gn_apply_transpose_kernel(const float* __restrict__ q,
                                          const float* __restrict__ stats,
                                          const float* __restrict__ gs,
                                          const float* __restrict__ gb,
                                          float* __restrict__ out) {
    __shared__ float tile[32][33];
    int l0 = blockIdx.x * 32, c0 = blockIdx.y * 32, b = blockIdx.z;
    int tx = threadIdx.x, ty = threadIdx.y;
    int c = c0 + ty;
    int g = c / CPG;
    float mean = stats[(b * NGROUPS + g) * 2];
    float rstd = stats[(b * NGROUPS + g) * 2 + 1];
    float v = q[((size_t)(b * DIM + c)) * SPATIAL + l0 + tx];
    tile[ty][tx] = (v - mean) * rstd * gs[c] + gb[c];
    __syncthreads();
    out[((size_t)(b * SPATIAL + l0 + ty)) * DIM + c0 + tx] = tile[tx][ty];
}

// ---------------------------------------------------------------------------
// Final: token layout -> NCHW, + residual q.
// ---------------------------------------------------------------------------
__global__ void out_transpose_kernel(const float* __restrict__ xin,
                                     const float* __restrict__ q,
                                     float* __restrict__ out) {
    __shared__ float tile[32][33];
    int l0 = blockIdx.x * 32, c0 = blockIdx.y * 32, b = blockIdx.z;
    int tx = threadIdx.x, ty = threadIdx.y;
    tile[ty][tx] = xin[((size_t)(b * SPATIAL + l0 + ty)) * DIM + c0 + tx];
    __syncthreads();
    size_t oi = ((size_t)(b * DIM + c0 + ty)) * SPATIAL + l0 + tx;
    out[oi] = tile[tx][ty] + q[oi];
}

// ---------------------------------------------------------------------------
// LayerNorm over rows of 320. One wave per row.
// ---------------------------------------------------------------------------
__global__ __launch_bounds__(64) void ln_kernel(const float* __restrict__ x,
                                                const float* __restrict__ sc,
                                                const float* __restrict__ bi,
                                                float* __restrict__ out) {
    int row = blockIdx.x;
    const float* xr = x + (size_t)row * DIM;
    float v[5];
    float sum = 0.f, sq = 0.f;
#pragma unroll
    for (int j = 0; j < 5; j++) {
        v[j] = xr[threadIdx.x + j * 64];
        sum += v[j]; sq += v[j] * v[j];
    }
#pragma unroll
    for (int off = 32; off > 0; off >>= 1) {
        sum += __shfl_down(sum, off);
        sq  += __shfl_down(sq, off);
    }
    sum = __shfl(sum, 0); sq = __shfl(sq, 0);
    float mean = sum / (float)DIM;
    float rstd = rsqrtf(sq / (float)DIM - mean * mean + 1e-5f);
#pragma unroll
    for (int j = 0; j < 5; j++) {
        int i = threadIdx.x + j * 64;
        out[(size_t)row * DIM + i] = (v[j] - mean) * rstd * sc[i] + bi[i];
    }
}

// ---------------------------------------------------------------------------
// Generic fp32 GEMM: C[M,N] = A[M,K] @ W[K,N] (+bias) (+resid)
// 64x64 tile, BK=16, 256 threads, 4x4 micro. LDS stride 68 -> aligned b128.
// ---------------------------------------------------------------------------
__global__ __launch_bounds__(256) void gemm_kernel(const float* __restrict__ A,
                                                   const float* __restrict__ W,
                                                   const float* __restrict__ bias,
                                                   const float* __restrict__ resid,
                                                   float* __restrict__ C,
                                                   int M, int N, int K) {
    __shared__ float As[16][68];
    __shared__ float Bs[16][68];
    int tid = threadIdx.x;
    int tx = tid & 15, ty = tid >> 4;
    int m0 = blockIdx.x * 64, n0 = blockIdx.y * 64;
    float acc[4][4] = {};
    for (int k0 = 0; k0 < K; k0 += 16) {
#pragma unroll
        for (int p = 0; p < 4; p++) {
            int lin = p * 256 + tid;
            int r = lin >> 4, cc = lin & 15;
            int m = m0 + r;
            As[cc][r] = (m < M) ? A[(size_t)m * K + k0 + cc] : 0.f;
        }
#pragma unroll
        for (int p = 0; p < 4; p++) {
            int lin = p * 256 + tid;
            int r = lin >> 6, cc = lin & 63;
            Bs[r][cc] = W[(size_t)(k0 + r) * N + n0 + cc];
        }
        __syncthreads();
#pragma unroll
        for (int kk = 0; kk < 16; kk++) {
            float a[4], bv[4];
#pragma unroll
            for (int i = 0; i < 4; i++) a[i] = As[kk][ty * 4 + i];
#pragma unroll
            for (int j = 0; j < 4; j++) bv[j] = Bs[kk][tx * 4 + j];
#pragma unroll
            for (int i = 0; i < 4; i++)
#pragma unroll
                for (int j = 0; j < 4; j++)
                    acc[i][j] += a[i] * bv[j];
        }
        __syncthreads();
    }
#pragma unroll
    for (int i = 0; i < 4; i++) {
        int m = m0 + ty * 4 + i;
        if (m >= M) continue;
#pragma unroll
        for (int j = 0; j < 4; j++) {
            int n = n0 + tx * 4 + j;
            float v = acc[i][j];
            if (bias)  v += bias[n];
            if (resid) v += resid[(size_t)m * N + n];
            C[(size_t)m * N + n] = v;
        }
    }
}

// ---------------------------------------------------------------------------
// fc0 + GEGLU fused. W is [K, 2*FF]. Output [M, FF]. Exact erf GELU.
// ---------------------------------------------------------------------------
__global__ __launch_bounds__(256) void gemm_geglu_kernel(const float* __restrict__ A,
                                                         const float* __restrict__ W,
                                                         const float* __restrict__ bias,
                                                         float* __restrict__ C,
                                                         int M, int K) {
    const int NW = 2 * FF;
    __shared__ float As[16][68];
    __shared__ float Bv[16][68];
    __shared__ float Bg[16][68];
    int tid = threadIdx.x;
    int tx = tid & 15, ty = tid >> 4;
    int m0 = blockIdx.x * 64, n0 = blockIdx.y * 64;
    float av[4][4] = {}, ag[4][4] = {};
    for (int k0 = 0; k0 < K; k0 += 16) {
#pragma unroll
        for (int p = 0; p < 4; p++) {
            int lin = p * 256 + tid;
            int r = lin >> 4, cc = lin & 15;
            As[cc][r] = A[(size_t)(m0 + r) * K + k0 + cc];
        }
#pragma unroll
        for (int p = 0; p < 4; p++) {
            int lin = p * 256 + tid;
            int r = lin >> 6, cc = lin & 63;
            Bv[r][cc] = W[(size_t)(k0 + r) * NW + n0 + cc];
            Bg[r][cc] = W[(size_t)(k0 + r) * NW + FF + n0 + cc];
        }
        __syncthreads();
#pragma unroll
        for (int kk = 0; kk < 16; kk++) {
            float a[4], bv[4], bg[4];
#pragma unroll
            for (int i = 0; i < 4; i++) a[i] = As[kk][ty * 4 + i];
#pragma unroll
            for (int j = 0; j < 4; j++) { bv[j] = Bv[kk][tx * 4 + j]; bg[j] = Bg[kk][tx * 4 + j]; }
#pragma unroll
            for (int i = 0; i < 4; i++)
#pragma unroll
                for (int j = 0; j < 4; j++) {
                    av[i][j] += a[i] * bv[j];
                    ag[i][j] += a[i] * bg[j];
                }
        }
        __syncthreads();
    }
#pragma unroll
    for (int i = 0; i < 4; i++) {
        int m = m0 + ty * 4 + i;
#pragma unroll
        for (int j = 0; j < 4; j++) {
            int n = n0 + tx * 4 + j;
            float val  = av[i][j] + bias[n];
            float gate = ag[i][j] + bias[n + FF];
            float g = 0.5f * gate * (1.f + erff(gate * 0.70710678118654752f));
            C[(size_t)m * FF + n] = val * g;
        }
    }
}

// ---------------------------------------------------------------------------
// Flash attention: grid (L/64, H, B), block 256. 64x64 Q/K tiles,
// K/V staged in LDS, online softmax, O accumulated in registers.
// Q,K,V token layout [rows, 320], head h = cols [h*40, h*40+40). nk keys/batch.
// ---------------------------------------------------------------------------
constexpr int TQ = 64;
constexpr int TK = 64;

__global__ __launch_bounds__(256) void flash_attn_kernel(const float* __restrict__ Q,
                                                         const float* __restrict__ Kp,
                                                         const float* __restrict__ Vp,
                                                         float* __restrict__ O,
                                                         int nk) {
    // Transposed (k-major) Q/K tiles, stride 68 -> aligned float4, 2-way banks.
    __shared__ float Qs[DH][68];
    __shared__ float Ks[DH][68];
    __shared__ float Vs[TK][DH];       // row-major, broadcast reads
    __shared__ float Ps[TQ][65];       // score/prob tile
    __shared__ float redm[4][65], reds[4][65];
    __shared__ float mtile[TQ], mrow[TQ], lrow[TQ], arow[TQ];

    int qt = blockIdx.x, h = blockIdx.y, b = blockIdx.z;
    int tid = threadIdx.x;
    int q0 = qt * TQ;
    const float scale = 0.15811388300841897f;  // 1/sqrt(40)

    // stage Q tile (scaled), transposed
    const float* Qbase = Q + ((size_t)(b * SPATIAL + q0)) * DIM + h * DH;
    for (int i = tid; i < TQ * DH; i += 256) {
        int r = i / DH, c = i - r * DH;
        Qs[c][r] = Qbase[(size_t)r * DIM + c] * scale;
    }
    if (tid < TQ) { mrow[tid] = -1e30f; lrow[tid] = 0.f; }

    float oacc[10];
#pragma unroll
    for (int c = 0; c < 10; c++) oacc[c] = 0.f;
    int orow = tid & 63, opart = tid >> 6;

    int tx = tid & 15, ty = tid >> 4;
    const float* Kb = Kp + (size_t)b * nk * DIM + h * DH;
    const float* Vb = Vp + (size_t)b * nk * DIM + h * DH;
    int ntiles = (nk + TK - 1) / TK;
    __syncthreads();

    for (int t = 0; t < ntiles; t++) {
        int k0 = t * TK;
        // stage K (transposed) and V (row-major)
        for (int i = tid; i < TK * DH; i += 256) {
            int r = i / DH, c = i - r * DH;
            int kr = k0 + r;
            float kval = 0.f, vval = 0.f;
            if (kr < nk) {
                kval = Kb[(size_t)kr * DIM + c];
                vval = Vb[(size_t)kr * DIM + c];
            }
            Ks[c][r] = kval;
            Vs[r][c] = vval;
        }
        __syncthreads();

        // scores: 64x64 = (64x40) @ (40x64), 4x4 micro per thread
        float s[4][4] = {};
#pragma unroll 8
        for (int k = 0; k < DH; k++) {
            float a[4], bb[4];
#pragma unroll
            for (int i = 0; i < 4; i++) a[i] = Qs[k][ty * 4 + i];
#pragma unroll
            for (int j = 0; j < 4; j++) bb[j] = Ks[k][tx * 4 + j];
#pragma unroll
            for (int i = 0; i < 4; i++)
#pragma unroll
                for (int j = 0; j < 4; j++)
                    s[i][j] += a[i] * bb[j];
        }
#pragma unroll
        for (int i = 0; i < 4; i++)
#pragma unroll
            for (int j = 0; j < 4; j++) {
                int col = tx * 4 + j;
                Ps[ty * 4 + i][col] = (k0 + col < nk) ? s[i][j] : -1e30f;
            }
        __syncthreads();

        // online softmax: 4 threads per row (16 cols each)
        {
            float pm = -1e30f;
            int cbase = opart * 16;
#pragma unroll
            for (int c = 0; c < 16; c++) pm = fmaxf(pm, Ps[orow][cbase + c]);
            redm[opart][orow] = pm;
        }
        __syncthreads();
        if (tid < TQ) {
            float mold = mrow[tid];
            float mt = fmaxf(fmaxf(redm[0][tid], redm[1][tid]),
                             fmaxf(redm[2][tid], redm[3][tid]));
            mt = fmaxf(mold, mt);
            arow[tid] = __expf(mold - mt);
            mrow[tid] = mt;
            mtile[tid] = mt;
        }
        __syncthreads();
        {
            float mt = mtile[orow];
            float psum = 0.f;
            int cbase = opart * 16;
#pragma unroll
            for (int c = 0; c < 16; c++) {
                float e = __expf(Ps[orow][cbase + c] - mt);
                Ps[orow][cbase + c] = e;
                psum += e;
            }
            reds[opart][orow] = psum;
        }
        __syncthreads();
        if (tid < TQ) {
            lrow[tid] = lrow[tid] * arow[tid] +
                        (reds[0][tid] + reds[1][tid] + reds[2][tid] + reds[3][tid]);
        }
        __syncthreads();

        // PV: O = O*alpha + P @ V ; thread owns (row orow, cols opart*10..+10)
        float alpha = arow[orow];
#pragma unroll
        for (int c = 0; c < 10; c++) oacc[c] *= alpha;
        int vc = opart * 10;
#pragma unroll 16
        for (int j = 0; j < TK; j++) {
            float p = Ps[orow][j];
#pragma unroll
            for (int c = 0; c < 10; c++) oacc[c] += p * Vs[j][vc + c];
        }
        __syncthreads();   // protect Ks/Vs/Ps for next tile
    }

    float inv = 1.f / lrow[orow];
    float* Ob = O + ((size_t)(b * SPATIAL + q0 + orow)) * DIM + h * DH + opart * 10;
#pragma unroll
    for (int c = 0; c < 10; c++) Ob[c] = oacc[c] * inv;
}

// ---------------------------------------------------------------------------
extern "C" void kernel_launch(void* const* d_in, const int* in_sizes, int n_in,
                              void* d_out, int out_size, void* d_ws, size_t ws_size,
                              hipStream_t stream) {
    (void)in_sizes; (void)n_in; (void)out_size; (void)ws_size;
    const float* q      = (const float*)d_in[0];
    const float* kv     = (const float*)d_in[1];
    const float* gn_s   = (const float*)d_in[2];
    const float* gn_b   = (const float*)d_in[3];
    const float* cin_w  = (const float*)d_in[4];
    const float* cin_b  = (const float*)d_in[5];
    const float* ln0_s  = (const float*)d_in[6];
    const float* ln0_b  = (const float*)d_in[7];
    const float* a1_wq  = (const float*)d_in[8];
    const float* a1_wk  = (const float*)d_in[9];
    const float* a1_wv  = (const float*)d_in[10];
    const float* a1_wo  = (const float*)d_in[11];
    const float* a1_bo  = (const float*)d_in[12];
    const float* ln1_s  = (const float*)d_in[13];
    const float* ln1_b  = (const float*)d_in[14];
    const float* a2_wq  = (const float*)d_in[15];
    const float* a2_wk  = (const float*)d_in[16];
    const float* a2_wv  = (const float*)d_in[17];
    const float* a2_wo  = (const float*)d_in[18];
    const float* a2_bo  = (const float*)d_in[19];
    const float* lnA_s  = (const float*)d_in[20];
    const float* lnA_b  = (const float*)d_in[21];
    const float* fc0_w  = (const float*)d_in[22];
    const float* fc0_b  = (const float*)d_in[23];
    const float* fc1_w  = (const float*)d_in[24];
    const float* fc1_b  = (const float*)d_in[25];
    const float* cout_w = (const float*)d_in[26];
    const float* cout_b = (const float*)d_in[27];
    float* out = (float*)d_out;

    float* ws = (float*)d_ws;
    const size_t BS = (size_t)ROWS * DIM;
    float* stats = ws;
    float* B0 = ws + 256;
    float* B1 = B0 + BS;
    float* B2 = B1 + BS;
    float* B3 = B2 + BS;
    float* B4 = B3 + BS;
    float* KK  = B4 + BS;
    float* KV_ = KK + (size_t)2 * KVL * DIM;
    float* GG  = KV_ + (size_t)2 * KVL * DIM;

    auto gemm = [&](const float* A, const float* W, const float* bias,
                    const float* resid, float* C, int M, int N, int K) {
        gemm_kernel<<<dim3((M + 63) / 64, N / 64), 256, 0, stream>>>(A, W, bias, resid, C, M, N, K);
    };

    // GroupNorm + transpose to tokens
    gn_stats_kernel<<<64, 256, 0, stream>>>(q, stats);
    gn_apply_transpose_kernel<<<dim3(SPATIAL / 32, DIM / 32, BATCH), dim3(32, 32), 0, stream>>>(
        q, stats, gn_s, gn_b, B1);
    gemm(B1, cin_w, cin_b, nullptr, B0, ROWS, DIM, DIM);

    // self-attention
    ln_kernel<<<ROWS, 64, 0, stream>>>(B0, ln0_s, ln0_b, B1);
    gemm(B1, a1_wq, nullptr, nullptr, B2, ROWS, DIM, DIM);
    gemm(B1, a1_wk, nullptr, nullptr, B3, ROWS, DIM, DIM);
    gemm(B1, a1_wv, nullptr, nullptr, B4, ROWS, DIM, DIM);
    flash_attn_kernel<<<dim3(SPATIAL / TQ, NHEADS, BATCH), 256, 0, stream>>>(B2, B3, B4, B1, SPATIAL);
    gemm(B1, a1_wo, a1_bo, B0, B0, ROWS, DIM, DIM);

    // cross-attention
    ln_kernel<<<ROWS, 64, 0, stream>>>(B0, ln1_s, ln1_b, B1);
    gemm(B1, a2_wq, nullptr, nullptr, B2, ROWS, DIM, DIM);
    gemm(kv, a2_wk, nullptr, nullptr, KK,  BATCH * KVL, DIM, KVD);
    gemm(kv, a2_wv, nullptr, nullptr, KV_, BATCH * KVL, DIM, KVD);
    flash_attn_kernel<<<dim3(SPATIAL / TQ, NHEADS, BATCH), 256, 0, stream>>>(B2, KK, KV_, B1, KVL);
    gemm(B1, a2_wo, a2_bo, B0, B0, ROWS, DIM, DIM);

    // FFN (GEGLU)
    ln_kernel<<<ROWS, 64, 0, stream>>>(B0, lnA_s, lnA_b, B1);
    gemm_geglu_kernel<<<dim3(ROWS / 64, FF / 64), 256, 0, stream>>>(B1, fc0_w, fc0_b, GG, ROWS, DIM);
    gemm(GG, fc1_w, fc1_b, B0, B1, ROWS, DIM, FF);

    // conv_out (1x1) + res1, back to NCHW
    gemm(B1, cout_w, cout_b, nullptr, B2, ROWS, DIM, DIM);
    out_transpose_kernel<<<dim3(SPATIAL / 32, DIM / 32, BATCH), dim3(32, 32), 0, stream>>>(B2, q, out);
}

// Round 3
// 958.425 us; speedup vs baseline: 11.3400x; 2.6172x over previous
//
#include <hip/hip_runtime.h>
#include <math.h>

typedef short short8 __attribute__((ext_vector_type(8)));
typedef float floatx4 __attribute__((ext_vector_type(4)));
typedef unsigned short ushort_t;
typedef unsigned int uint_t;

// ---- problem constants ----
constexpr int BATCH   = 2;
constexpr int DIM     = 320;
constexpr int NHEADS  = 8;
constexpr int DH      = 40;
constexpr int NGROUPS = 32;
constexpr int CPG     = 10;
constexpr int SPATIAL = 4096;
constexpr int ROWS    = BATCH * SPATIAL;   // 8192
constexpr int KVL     = 77;
constexpr int KVD     = 768;
constexpr int FF      = 1280;              // geglu half width

__device__ __forceinline__ ushort_t f2bf(float f) {
    uint_t u = __float_as_uint(f);
    u += 0x7FFFu + ((u >> 16) & 1u);       // RNE
    return (ushort_t)(u >> 16);
}
__device__ __forceinline__ float bf2f(ushort_t u) {
    return __uint_as_float(((uint_t)u) << 16);
}

// ---------------------------------------------------------------------------
// stats zero (harness re-poisons ws each replay)
// ---------------------------------------------------------------------------
__global__ void zero_stats_kernel(float* stats) {
    if (threadIdx.x < 128) stats[threadIdx.x] = 0.f;
}

// ---------------------------------------------------------------------------
// GroupNorm partial sums: grid (16 slices, 64 groups), atomics into stats.
// ---------------------------------------------------------------------------
__global__ __launch_bounds__(256) void gn_partial_kernel(const float* __restrict__ q,
                                                         float* __restrict__ stats) {
    int slice = blockIdx.x, bg = blockIdx.y;
    const float* base = q + (size_t)bg * (CPG * SPATIAL) + slice * 2560;
    float s = 0.f, ss = 0.f;
#pragma unroll
    for (int j = 0; j < 10; j++) {
        float v = base[j * 256 + threadIdx.x];
        s += v; ss += v * v;
    }
    __shared__ float rs[256], rss[256];
    rs[threadIdx.x] = s; rss[threadIdx.x] = ss;
    __syncthreads();
    for (int off = 128; off > 0; off >>= 1) {
        if (threadIdx.x < off) {
            rs[threadIdx.x]  += rs[threadIdx.x + off];
            rss[threadIdx.x] += rss[threadIdx.x + off];
        }
        __syncthreads();
    }
    if (threadIdx.x == 0) {
        atomicAdd(&stats[bg * 2],     rs[0]);
        atomicAdd(&stats[bg * 2 + 1], rss[0]);
    }
}

// ---------------------------------------------------------------------------
// GN apply + transpose NCHW -> (b,l,c) tokens, bf16 out.
// ---------------------------------------------------------------------------
__global__ void gn_apply_transpose_kernel(const float* __restrict__ q,
                                          const float* __restrict__ stats,
                                          const float* __restrict__ gs,
                                          const float* __restrict__ gb,
                                          ushort_t* __restrict__ out) {
    __shared__ float tile[32][33];
    int l0 = blockIdx.x * 32, c0 = blockIdx.y * 32, b = blockIdx.z;
    int tx = threadIdx.x, ty = threadIdx.y;
    int c = c0 + ty;
    int g = c / CPG;
    float s  = stats[(b * NGROUPS + g) * 2];
    float ss = stats[(b * NGROUPS + g) * 2 + 1];
    const float invn = 1.f / 40960.f;
    float mean = s * invn;
    float rstd = rsqrtf(ss * invn - mean * mean + 1e-6f);
    float v = q[((size_t)(b * DIM + c)) * SPATIAL + l0 + tx];
    tile[ty][tx] = (v - mean) * rstd * gs[c] + gb[c];
    __syncthreads();
    out[((size_t)(b * SPATIAL + l0 + ty)) * DIM + c0 + tx] = f2bf(tile[tx][ty]);
}

// ---------------------------------------------------------------------------
// tokens f32 -> NCHW + residual q
// ---------------------------------------------------------------------------
__global__ void out_transpose_kernel(const float* __restrict__ xin,
                                     const float* __restrict__ q,
                                     float* __restrict__ out) {
    __shared__ float tile[32][33];
    int l0 = blockIdx.x * 32, c0 = blockIdx.y * 32, b = blockIdx.z;
    int tx = threadIdx.x, ty = threadIdx.y;
    tile[ty][tx] = xin[((size_t)(b * SPATIAL + l0 + ty)) * DIM + c0 + tx];
    __syncthreads();
    size_t oi = ((size_t)(b * DIM + c0 + ty)) * SPATIAL + l0 + tx;
    out[oi] = tile[tx][ty] + q[oi];
}

// ---------------------------------------------------------------------------
// LayerNorm rows of 320, f32 in, bf16 out. One wave per row.
// ---------------------------------------------------------------------------
__global__ __launch_bounds__(64) void ln_kernel(const float* __restrict__ x,
                                                const float* __restrict__ sc,
                                                const float* __restrict__ bi,
                                                ushort_t* __restrict__ out) {
    int row = blockIdx.x;
    const float* xr = x + (size_t)row * DIM;
    float v[5];
    float sum = 0.f, sq = 0.f;
#pragma unroll
    for (int j = 0; j < 5; j++) {
        v[j] = xr[threadIdx.x + j * 64];
        sum += v[j]; sq += v[j] * v[j];
    }
#pragma unroll
    for (int off = 32; off > 0; off >>= 1) {
        sum += __shfl_down(sum, off);
        sq  += __shfl_down(sq, off);
    }
    sum = __shfl(sum, 0); sq = __shfl(sq, 0);
    float mean = sum / (float)DIM;
    float rstd = rsqrtf(sq / (float)DIM - mean * mean + 1e-5f);
#pragma unroll
    for (int j = 0; j < 5; j++) {
        int i = threadIdx.x + j * 64;
        out[(size_t)row * DIM + i] = f2bf((v[j] - mean) * rstd * sc[i] + bi[i]);
    }
}

// ---------------------------------------------------------------------------
// Weight transpose+convert: src f32 [K][N] -> dst bf16 [N][K]
// ---------------------------------------------------------------------------
__global__ void wtrans_kernel(const float* __restrict__ src, ushort_t* __restrict__ dst,
                              int K, int N) {
    __shared__ float tile[32][33];
    int n0 = blockIdx.x * 32, k0 = blockIdx.y * 32;
    int tx = threadIdx.x, ty = threadIdx.y;
    tile[ty][tx] = src[(size_t)(k0 + ty) * N + n0 + tx];
    __syncthreads();
    dst[(size_t)(n0 + ty) * K + k0 + tx] = f2bf(tile[tx][ty]);
}

// ---------------------------------------------------------------------------
// f32 -> bf16 elementwise
// ---------------------------------------------------------------------------
__global__ void cvt_bf16_kernel(const float* __restrict__ src, ushort_t* __restrict__ dst, int n) {
    int i = blockIdx.x * 256 + threadIdx.x;
    if (i < n) dst[i] = f2bf(src[i]);
}

// ---------------------------------------------------------------------------
// bf16 MFMA GEMM: C[M,N] = A[M,K](bf16) @ Wt[N,K](bf16)^T (+bias f32)(+resid f32)
// Outputs: Cf (f32) and/or Cb (bf16), either may be null.
// Tiles 64x64x64, 256 threads = 4 waves, wave w owns rows [16w,16w+16).
// ---------------------------------------------------------------------------
__global__ __launch_bounds__(256) void gemm_bf16_kernel(
    const ushort_t* __restrict__ A, const ushort_t* __restrict__ Wt,
    const float* __restrict__ bias, const float* __restrict__ resid,
    float* __restrict__ Cf, ushort_t* __restrict__ Cb,
    int M, int N, int K)
{
    __shared__ __align__(16) ushort_t As[64][72];
    __shared__ __align__(16) ushort_t Bs[64][72];
    int tid = threadIdx.x;
    int wave = tid >> 6, l15 = tid & 15, quad = (tid & 63) >> 4;
    int m0 = blockIdx.x * 64, n0 = blockIdx.y * 64;
    floatx4 acc[4] = {};

    for (int k0 = 0; k0 < K; k0 += 64) {
#pragma unroll
        for (int p = 0; p < 2; p++) {
            int lin = p * 256 + tid;
            int r = lin >> 3, c8 = (lin & 7) * 8;
            int m = m0 + r;
            short8 av = {};
            if (m < M) av = *(const short8*)&A[(size_t)m * K + k0 + c8];
            *(short8*)&As[r][c8] = av;
            *(short8*)&Bs[r][c8] = *(const short8*)&Wt[(size_t)(n0 + r) * K + k0 + c8];
        }
        __syncthreads();
        short8 a0 = *(const short8*)&As[16 * wave + l15][quad * 8];
        short8 a1 = *(const short8*)&As[16 * wave + l15][32 + quad * 8];
#pragma unroll
        for (int t = 0; t < 4; t++) {
            short8 b0 = *(const short8*)&Bs[16 * t + l15][quad * 8];
            short8 b1 = *(const short8*)&Bs[16 * t + l15][32 + quad * 8];
            acc[t] = __builtin_amdgcn_mfma_f32_16x16x32_bf16(a0, b0, acc[t], 0, 0, 0);
            acc[t] = __builtin_amdgcn_mfma_f32_16x16x32_bf16(a1, b1, acc[t], 0, 0, 0);
        }
        __syncthreads();
    }

    int mrow = m0 + 16 * wave + quad * 4;
#pragma unroll
    for (int t = 0; t < 4; t++) {
        int n = n0 + 16 * t + l15;
        float bv = bias ? bias[n] : 0.f;
#pragma unroll
        for (int i = 0; i < 4; i++) {
            int m = mrow + i;
            if (m < M) {
                float v = acc[t][i] + bv;
                if (resid) v += resid[(size_t)m * N + n];
                if (Cf) Cf[(size_t)m * N + n] = v;
                if (Cb) Cb[(size_t)m * N + n] = f2bf(v);
            }
        }
    }
}

// ---------------------------------------------------------------------------
// fc0 + GEGLU fused MFMA GEMM. A[M,320]bf16, Wt[2560][320]bf16.
// Block computes value tile (cols n0..n0+64) and gate tile (cols FF+n0..).
// Out: C[M,FF] bf16 = val * gelu(gate), exact erf.
// ---------------------------------------------------------------------------
__global__ __launch_bounds__(256) void gemm_geglu_bf16_kernel(
    const ushort_t* __restrict__ A, const ushort_t* __restrict__ Wt,
    const float* __restrict__ bias, ushort_t* __restrict__ C, int M)
{
    constexpr int K = 320;
    __shared__ __align__(16) ushort_t As[64][72];
    __shared__ __align__(16) ushort_t Bv[64][72];
    __shared__ __align__(16) ushort_t Bg[64][72];
    int tid = threadIdx.x;
    int wave = tid >> 6, l15 = tid & 15, quad = (tid & 63) >> 4;
    int m0 = blockIdx.x * 64, n0 = blockIdx.y * 64;
    floatx4 av[4] = {}, ag[4] = {};

    for (int k0 = 0; k0 < K; k0 += 64) {
#pragma unroll
        for (int p = 0; p < 2; p++) {
            int lin = p * 256 + tid;
            int r = lin >> 3, c8 = (lin & 7) * 8;
            *(short8*)&As[r][c8] = *(const short8*)&A[(size_t)(m0 + r) * K + k0 + c8];
            *(short8*)&Bv[r][c8] = *(const short8*)&Wt[(size_t)(n0 + r) * K + k0 + c8];
            *(short8*)&Bg[r][c8] = *(const short8*)&Wt[(size_t)(FF + n0 + r) * K + k0 + c8];
        }
        __syncthreads();
        short8 a0 = *(const short8*)&As[16 * wave + l15][quad * 8];
        short8 a1 = *(const short8*)&As[16 * wave + l15][32 + quad * 8];
#pragma unroll
        for (int t = 0; t < 4; t++) {
            short8 b0 = *(const short8*)&Bv[16 * t + l15][quad * 8];
            short8 b1 = *(const short8*)&Bv[16 * t + l15][32 + quad * 8];
            av[t] = __builtin_amdgcn_mfma_f32_16x16x32_bf16(a0, b0, av[t], 0, 0, 0);
            av[t] = __builtin_amdgcn_mfma_f32_16x16x32_bf16(a1, b1, av[t], 0, 0, 0);
            short8 g0 = *(const short8*)&Bg[16 * t + l15][quad * 8];
            short8 g1 = *(const short8*)&Bg[16 * t + l15][32 + quad * 8];
            ag[t] = __builtin_amdgcn_mfma_f32_16x16x32_bf16(a0, g0, ag[t], 0, 0, 0);
            ag[t] = __builtin_amdgcn_mfma_f32_16x16x32_bf16(a1, g1, ag[t], 0, 0, 0);
        }
        __syncthreads();
    }

    int mrow = m0 + 16 * wave + quad * 4;
#pragma unroll
    for (int t = 0; t < 4; t++) {
        int n = n0 + 16 * t + l15;
        float bv = bias[n], bg = bias[FF + n];
#pragma unroll
        for (int i = 0; i < 4; i++) {
            int m = mrow + i;
            float val  = av[t][i] + bv;
            float gate = ag[t][i] + bg;
            float g = 0.5f * gate * (1.f + erff(gate * 0.70710678118654752f));
            C[(size_t)m * FF + n] = f2bf(val * g);
        }
    }
}

// ---------------------------------------------------------------------------
// MFMA flash attention. grid (L/64, H, B), 256 threads = 4 waves.
// Q/K/V bf16 with row strides sQ/sKV, head offset h*DH baked via pointer math.
// dh=40 padded to 64 (QK) / 48 (PV). Softmax state in registers (C/D rows).
// O bf16 [rows,320].
// ---------------------------------------------------------------------------
__global__ __launch_bounds__(256) void flash_mfma_kernel(
    const ushort_t* __restrict__ Qg, const ushort_t* __restrict__ Kg,
    const ushort_t* __restrict__ Vg, ushort_t* __restrict__ Og,
    int sQ, int sKV, int nk)
{
    __shared__ __align__(16) ushort_t Qs[64][72];
    __shared__ __align__(16) ushort_t Ks[64][72];
    __shared__ __align__(16) ushort_t VsT[48][72];
    __shared__ __align__(16) ushort_t Ps[64][72];

    int tid = threadIdx.x;
    int wave = tid >> 6, l15 = tid & 15, quad = (tid & 63) >> 4;
    int q0 = blockIdx.x * 64, h = blockIdx.y, b = blockIdx.z;

    const ushort_t* Qb = Qg + (size_t)(b * SPATIAL + q0) * sQ + h * DH;
    const ushort_t* Kb = Kg + (size_t)b * nk * sKV + h * DH;
    const ushort_t* Vb = Vg + (size_t)b * nk * sKV + h * DH;

    for (int i = tid; i < 64 * 64; i += 256) {
        int r = i >> 6, c = i & 63;
        Qs[r][c] = (c < DH) ? Qb[(size_t)r * sQ + c] : (ushort_t)0;
    }
    __syncthreads();
    short8 aq0 = *(const short8*)&Qs[16 * wave + l15][quad * 8];
    short8 aq1 = *(const short8*)&Qs[16 * wave + l15][32 + quad * 8];

    const float scale = 0.15811388300841897f;  // 1/sqrt(40)
    float mrow[4], lrow[4];
#pragma unroll
    for (int i = 0; i < 4; i++) { mrow[i] = -1e30f; lrow[i] = 0.f; }
    floatx4 o[3] = {};

    int ntiles = (nk + 63) >> 6;
    for (int t = 0; t < ntiles; t++) {
        int k0 = t * 64;
        __syncthreads();   // protect Ks/VsT from previous iteration's readers
        for (int i = tid; i < 64 * 64; i += 256) {
            int r = i >> 6, c = i & 63;
            int kr = k0 + r;
            Ks[r][c] = (kr < nk && c < DH) ? Kb[(size_t)kr * sKV + c] : (ushort_t)0;
        }
        for (int i = tid; i < 48 * 64; i += 256) {
            int k = i / 48, c = i - k * 48;
            int kr = k0 + k;
            VsT[c][k] = (kr < nk && c < DH) ? Vb[(size_t)kr * sKV + c] : (ushort_t)0;
        }
        __syncthreads();

        // S = Q K^T (scaled later), 4 n-tiles of 16 keys
        floatx4 s[4] = {};
#pragma unroll
        for (int tt = 0; tt < 4; tt++) {
            short8 b0 = *(const short8*)&Ks[16 * tt + l15][quad * 8];
            short8 b1 = *(const short8*)&Ks[16 * tt + l15][32 + quad * 8];
            s[tt] = __builtin_amdgcn_mfma_f32_16x16x32_bf16(aq0, b0, s[tt], 0, 0, 0);
            s[tt] = __builtin_amdgcn_mfma_f32_16x16x32_bf16(aq1, b1, s[tt], 0, 0, 0);
        }
        float sv[4][4];
#pragma unroll
        for (int tt = 0; tt < 4; tt++) {
            int col = k0 + 16 * tt + l15;
#pragma unroll
            for (int i = 0; i < 4; i++)
                sv[tt][i] = (col < nk) ? s[tt][i] * scale : -1e30f;
        }

        // online softmax per row (row = quad*4+i, shared by 16 lanes of same quad)
        float al[4];
#pragma unroll
        for (int i = 0; i < 4; i++) {
            float mx = fmaxf(fmaxf(sv[0][i], sv[1][i]), fmaxf(sv[2][i], sv[3][i]));
#pragma unroll
            for (int msk = 1; msk < 16; msk <<= 1) mx = fmaxf(mx, __shfl_xor(mx, msk));
            float mn = fmaxf(mrow[i], mx);
            al[i] = __expf(mrow[i] - mn);
            mrow[i] = mn;
            float rs = 0.f;
#pragma unroll
            for (int tt = 0; tt < 4; tt++) {
                float p = __expf(sv[tt][i] - mn);
                Ps[16 * wave + quad * 4 + i][16 * tt + l15] = f2bf(p);
                rs += p;
            }
#pragma unroll
            for (int msk = 1; msk < 16; msk <<= 1) rs += __shfl_xor(rs, msk);
            lrow[i] = lrow[i] * al[i] + rs;
        }

        // rescale O, then O += P V   (P rows are wave-private; lgkm wait is automatic)
#pragma unroll
        for (int t2 = 0; t2 < 3; t2++)
#pragma unroll
            for (int i = 0; i < 4; i++) o[t2][i] *= al[i];

        short8 p0 = *(const short8*)&Ps[16 * wave + l15][quad * 8];
        short8 p1 = *(const short8*)&Ps[16 * wave + l15][32 + quad * 8];
#pragma unroll
        for (int t2 = 0; t2 < 3; t2++) {
            short8 b0 = *(const short8*)&VsT[16 * t2 + l15][quad * 8];
            short8 b1 = *(const short8*)&VsT[16 * t2 + l15][32 + quad * 8];
            o[t2] = __builtin_amdgcn_mfma_f32_16x16x32_bf16(p0, b0, o[t2], 0, 0, 0);
            o[t2] = __builtin_amdgcn_mfma_f32_16x16x32_bf16(p1, b1, o[t2], 0, 0, 0);
        }
    }

    float inv[4];
#pragma unroll
    for (int i = 0; i < 4; i++) inv[i] = 1.f / lrow[i];
#pragma unroll
    for (int t2 = 0; t2 < 3; t2++) {
        int c = 16 * t2 + l15;
        if (c < DH) {
#pragma unroll
            for (int i = 0; i < 4; i++) {
                size_t row = (size_t)(b * SPATIAL + q0 + 16 * wave + quad * 4 + i);
                Og[row * DIM + h * DH + c] = f2bf(o[t2][i] * inv[i]);
            }
        }
    }
}

// ---------------------------------------------------------------------------
extern "C" void kernel_launch(void* const* d_in, const int* in_sizes, int n_in,
                              void* d_out, int out_size, void* d_ws, size_t ws_size,
                              hipStream_t stream) {
    (void)in_sizes; (void)n_in; (void)out_size; (void)ws_size;
    const float* q      = (const float*)d_in[0];
    const float* kv     = (const float*)d_in[1];
    const float* gn_s   = (const float*)d_in[2];
    const float* gn_b   = (const float*)d_in[3];
    const float* cin_w  = (const float*)d_in[4];
    const float* cin_b  = (const float*)d_in[5];
    const float* ln0_s  = (const float*)d_in[6];
    const float* ln0_b  = (const float*)d_in[7];
    const float* a1_wq  = (const float*)d_in[8];
    const float* a1_wk  = (const float*)d_in[9];
    const float* a1_wv  = (const float*)d_in[10];
    const float* a1_wo  = (const float*)d_in[11];
    const float* a1_bo  = (const float*)d_in[12];
    const float* ln1_s  = (const float*)d_in[13];
    const float* ln1_b  = (const float*)d_in[14];
    const float* a2_wq  = (const float*)d_in[15];
    const float* a2_wk  = (const float*)d_in[16];
    const float* a2_wv  = (const float*)d_in[17];
    const float* a2_wo  = (const float*)d_in[18];
    const float* a2_bo  = (const float*)d_in[19];
    const float* lnA_s  = (const float*)d_in[20];
    const float* lnA_b  = (const float*)d_in[21];
    const float* fc0_w  = (const float*)d_in[22];
    const float* fc0_b  = (const float*)d_in[23];
    const float* fc1_w  = (const float*)d_in[24];
    const float* fc1_b  = (const float*)d_in[25];
    const float* cout_w = (const float*)d_in[26];
    const float* cout_b = (const float*)d_in[27];
    float* out = (float*)d_out;

    // ---- workspace carve (256B aligned chunks) ----
    char* p = (char*)d_ws;
    auto carve = [&](size_t bytes) -> char* {
        char* r = p;
        p += (bytes + 255) & ~(size_t)255;
        return r;
    };
    float*    stats  = (float*)carve(512);
    float*    B0     = (float*)carve((size_t)ROWS * DIM * 4);       // residual stream f32
    float*    B2     = (float*)carve((size_t)ROWS * DIM * 4);       // conv_out result f32
    ushort_t* gnO    = (ushort_t*)carve((size_t)ROWS * DIM * 2);
    ushort_t* ln0O   = (ushort_t*)carve((size_t)ROWS * DIM * 2);
    ushort_t* QKV    = (ushort_t*)carve((size_t)ROWS * 960 * 2);
    ushort_t* attnO  = (ushort_t*)carve((size_t)ROWS * DIM * 2);
    ushort_t* ln1O   = (ushort_t*)carve((size_t)ROWS * DIM * 2);
    ushort_t* Q2     = (ushort_t*)carve((size_t)ROWS * DIM * 2);
    ushort_t* KVc    = (ushort_t*)carve((size_t)BATCH * KVL * 640 * 2);
    ushort_t* lnAO   = (ushort_t*)carve((size_t)ROWS * DIM * 2);
    ushort_t* GLU    = (ushort_t*)carve((size_t)ROWS * FF * 2);
    ushort_t* X2     = (ushort_t*)carve((size_t)ROWS * DIM * 2);
    ushort_t* kvbf   = (ushort_t*)carve((size_t)BATCH * KVL * KVD * 2);
    ushort_t* qkv_t  = (ushort_t*)carve((size_t)960 * 320 * 2);
    ushort_t* cin_t  = (ushort_t*)carve((size_t)320 * 320 * 2);
    ushort_t* a1wo_t = (ushort_t*)carve((size_t)320 * 320 * 2);
    ushort_t* a2wq_t = (ushort_t*)carve((size_t)320 * 320 * 2);
    ushort_t* kvx_t  = (ushort_t*)carve((size_t)640 * 768 * 2);
    ushort_t* a2wo_t = (ushort_t*)carve((size_t)320 * 320 * 2);
    ushort_t* fc0_t  = (ushort_t*)carve((size_t)2560 * 320 * 2);
    ushort_t* fc1_t  = (ushort_t*)carve((size_t)320 * 1280 * 2);
    ushort_t* cout_t = (ushort_t*)carve((size_t)320 * 320 * 2);

    dim3 b32(32, 32);
    auto wtrans = [&](const float* src, ushort_t* dst, int K, int N) {
        wtrans_kernel<<<dim3(N / 32, K / 32), b32, 0, stream>>>(src, dst, K, N);
    };
    auto gemm = [&](const ushort_t* A, const ushort_t* Wt, const float* bias,
                    const float* resid, float* Cf, ushort_t* Cb, int M, int N, int K) {
        gemm_bf16_kernel<<<dim3((M + 63) / 64, N / 64), 256, 0, stream>>>(
            A, Wt, bias, resid, Cf, Cb, M, N, K);
    };

    // ---- weight prep (bf16, transposed to [N][K]) ----
    wtrans(cin_w,  cin_t,  320, 320);
    wtrans(a1_wq,  qkv_t,              320, 320);
    wtrans(a1_wk,  qkv_t + 320 * 320,  320, 320);
    wtrans(a1_wv,  qkv_t + 640 * 320,  320, 320);
    wtrans(a1_wo,  a1wo_t, 320, 320);
    wtrans(a2_wq,  a2wq_t, 320, 320);
    wtrans(a2_wk,  kvx_t,              768, 320);
    wtrans(a2_wv,  kvx_t + 320 * 768,  768, 320);
    wtrans(a2_wo,  a2wo_t, 320, 320);
    wtrans(fc0_w,  fc0_t,  320, 2560);
    wtrans(fc1_w,  fc1_t,  1280, 320);
    wtrans(cout_w, cout_t, 320, 320);
    {
        int n = BATCH * KVL * KVD;
        cvt_bf16_kernel<<<(n + 255) / 256, 256, 0, stream>>>(kv, kvbf, n);
    }

    // ---- GroupNorm + conv_in ----
    zero_stats_kernel<<<1, 128, 0, stream>>>(stats);
    gn_partial_kernel<<<dim3(16, 64), 256, 0, stream>>>(q, stats);
    gn_apply_transpose_kernel<<<dim3(SPATIAL / 32, DIM / 32, BATCH), b32, 0, stream>>>(
        q, stats, gn_s, gn_b, gnO);
    gemm(gnO, cin_t, cin_b, nullptr, B0, nullptr, ROWS, DIM, DIM);

    // ---- self-attention ----
    ln_kernel<<<ROWS, 64, 0, stream>>>(B0, ln0_s, ln0_b, ln0O);
    gemm(ln0O, qkv_t, nullptr, nullptr, nullptr, QKV, ROWS, 960, DIM);
    flash_mfma_kernel<<<dim3(SPATIAL / 64, NHEADS, BATCH), 256, 0, stream>>>(
        QKV, QKV + 320, QKV + 640, attnO, 960, 960, SPATIAL);
    gemm(attnO, a1wo_t, a1_bo, B0, B0, nullptr, ROWS, DIM, DIM);

    // ---- cross-attention ----
    ln_kernel<<<ROWS, 64, 0, stream>>>(B0, ln1_s, ln1_b, ln1O);
    gemm(ln1O, a2wq_t, nullptr, nullptr, nullptr, Q2, ROWS, DIM, DIM);
    gemm(kvbf, kvx_t, nullptr, nullptr, nullptr, KVc, BATCH * KVL, 640, KVD);
    flash_mfma_kernel<<<dim3(SPATIAL / 64, NHEADS, BATCH), 256, 0, stream>>>(
        Q2, KVc, KVc + 320, attnO, 320, 640, KVL);
    gemm(attnO, a2wo_t, a2_bo, B0, B0, nullptr, ROWS, DIM, DIM);

    // ---- FFN (GEGLU) ----
    ln_kernel<<<ROWS, 64, 0, stream>>>(B0, lnA_s, lnA_b, lnAO);
    gemm_geglu_bf16_kernel<<<dim3(ROWS / 64, FF / 64), 256, 0, stream>>>(
        lnAO, fc0_t, fc0_b, GLU, ROWS);
    gemm(GLU, fc1_t, fc1_b, B0, nullptr, X2, ROWS, DIM, FF);

    // ---- conv_out + res1 ----
    gemm(X2, cout_t, cout_b, nullptr, B2, nullptr, ROWS, DIM, DIM);
    out_transpose_kernel<<<dim3(SPATIAL / 32, DIM / 32, BATCH), b32, 0, stream>>>(B2, q, out);
}

// Round 4
// 568.619 us; speedup vs baseline: 19.1139x; 1.6855x over previous
//
#include <hip/hip_runtime.h>
#include <math.h>

typedef short short8 __attribute__((ext_vector_type(8)));
typedef float floatx4 __attribute__((ext_vector_type(4)));
typedef unsigned short ushort_t;
typedef unsigned int uint_t;

// ---- problem constants ----
constexpr int BATCH   = 2;
constexpr int DIM     = 320;
constexpr int NHEADS  = 8;
constexpr int DH      = 40;
constexpr int NGROUPS = 32;
constexpr int CPG     = 10;
constexpr int SPATIAL = 4096;
constexpr int ROWS    = BATCH * SPATIAL;   // 8192
constexpr int KVL     = 77;
constexpr int KVD     = 768;
constexpr int FF      = 1280;              // geglu half width
constexpr int TQ      = 128;               // flash q-tile

__device__ __forceinline__ ushort_t f2bf(float f) {
    uint_t u = __float_as_uint(f);
    u += 0x7FFFu + ((u >> 16) & 1u);       // RNE
    return (ushort_t)(u >> 16);
}

// ---------------------------------------------------------------------------
__global__ void zero_stats_kernel(float* stats) {
    if (threadIdx.x < 128) stats[threadIdx.x] = 0.f;
}

// ---------------------------------------------------------------------------
// GroupNorm partial sums: grid (16 slices, 64 groups), atomics into stats.
// ---------------------------------------------------------------------------
__global__ __launch_bounds__(256) void gn_partial_kernel(const float* __restrict__ q,
                                                         float* __restrict__ stats) {
    int slice = blockIdx.x, bg = blockIdx.y;
    const float* base = q + (size_t)bg * (CPG * SPATIAL) + slice * 2560;
    float s = 0.f, ss = 0.f;
#pragma unroll
    for (int j = 0; j < 10; j++) {
        float v = base[j * 256 + threadIdx.x];
        s += v; ss += v * v;
    }
    __shared__ float rs[256], rss[256];
    rs[threadIdx.x] = s; rss[threadIdx.x] = ss;
    __syncthreads();
    for (int off = 128; off > 0; off >>= 1) {
        if (threadIdx.x < off) {
            rs[threadIdx.x]  += rs[threadIdx.x + off];
            rss[threadIdx.x] += rss[threadIdx.x + off];
        }
        __syncthreads();
    }
    if (threadIdx.x == 0) {
        atomicAdd(&stats[bg * 2],     rs[0]);
        atomicAdd(&stats[bg * 2 + 1], rss[0]);
    }
}

// ---------------------------------------------------------------------------
// GN apply + transpose NCHW -> (b,l,c) tokens, bf16 out.
// ---------------------------------------------------------------------------
__global__ void gn_apply_transpose_kernel(const float* __restrict__ q,
                                          const float* __restrict__ stats,
                                          const float* __restrict__ gs,
                                          const float* __restrict__ gb,
                                          ushort_t* __restrict__ out) {
    __shared__ float tile[32][33];
    int l0 = blockIdx.x * 32, c0 = blockIdx.y * 32, b = blockIdx.z;
    int tx = threadIdx.x, ty = threadIdx.y;
    int c = c0 + ty;
    int g = c / CPG;
    float s  = stats[(b * NGROUPS + g) * 2];
    float ss = stats[(b * NGROUPS + g) * 2 + 1];
    const float invn = 1.f / 40960.f;
    float mean = s * invn;
    float rstd = rsqrtf(ss * invn - mean * mean + 1e-6f);
    float v = q[((size_t)(b * DIM + c)) * SPATIAL + l0 + tx];
    tile[ty][tx] = (v - mean) * rstd * gs[c] + gb[c];
    __syncthreads();
    out[((size_t)(b * SPATIAL + l0 + ty)) * DIM + c0 + tx] = f2bf(tile[tx][ty]);
}

// ---------------------------------------------------------------------------
// tokens f32 -> NCHW + residual q
// ---------------------------------------------------------------------------
__global__ void out_transpose_kernel(const float* __restrict__ xin,
                                     const float* __restrict__ q,
                                     float* __restrict__ out) {
    __shared__ float tile[32][33];
    int l0 = blockIdx.x * 32, c0 = blockIdx.y * 32, b = blockIdx.z;
    int tx = threadIdx.x, ty = threadIdx.y;
    tile[ty][tx] = xin[((size_t)(b * SPATIAL + l0 + ty)) * DIM + c0 + tx];
    __syncthreads();
    size_t oi = ((size_t)(b * DIM + c0 + ty)) * SPATIAL + l0 + tx;
    out[oi] = tile[tx][ty] + q[oi];
}

// ---------------------------------------------------------------------------
// LayerNorm rows of 320, f32 in, bf16 out. One wave per row.
// ---------------------------------------------------------------------------
__global__ __launch_bounds__(64) void ln_kernel(const float* __restrict__ x,
                                                const float* __restrict__ sc,
                                                const float* __restrict__ bi,
                                                ushort_t* __restrict__ out) {
    int row = blockIdx.x;
    const float* xr = x + (size_t)row * DIM;
    float v[5];
    float sum = 0.f, sq = 0.f;
#pragma unroll
    for (int j = 0; j < 5; j++) {
        v[j] = xr[threadIdx.x + j * 64];
        sum += v[j]; sq += v[j] * v[j];
    }
#pragma unroll
    for (int off = 32; off > 0; off >>= 1) {
        sum += __shfl_down(sum, off);
        sq  += __shfl_down(sq, off);
    }
    sum = __shfl(sum, 0); sq = __shfl(sq, 0);
    float mean = sum / (float)DIM;
    float rstd = rsqrtf(sq / (float)DIM - mean * mean + 1e-5f);
#pragma unroll
    for (int j = 0; j < 5; j++) {
        int i = threadIdx.x + j * 64;
        out[(size_t)row * DIM + i] = f2bf((v[j] - mean) * rstd * sc[i] + bi[i]);
    }
}

// ---------------------------------------------------------------------------
// Weight transpose+convert: src f32 [K][N] -> dst bf16 [N][K]
// ---------------------------------------------------------------------------
__global__ void wtrans_kernel(const float* __restrict__ src, ushort_t* __restrict__ dst,
                              int K, int N) {
    __shared__ float tile[32][33];
    int n0 = blockIdx.x * 32, k0 = blockIdx.y * 32;
    int tx = threadIdx.x, ty = threadIdx.y;
    tile[ty][tx] = src[(size_t)(k0 + ty) * N + n0 + tx];
    __syncthreads();
    dst[(size_t)(n0 + ty) * K + k0 + tx] = f2bf(tile[tx][ty]);
}

__global__ void cvt_bf16_kernel(const float* __restrict__ src, ushort_t* __restrict__ dst, int n) {
    int i = blockIdx.x * 256 + threadIdx.x;
    if (i < n) dst[i] = f2bf(src[i]);
}

// ---------------------------------------------------------------------------
// bf16 MFMA GEMM: C[M,N] = A[M,K](bf16) @ Wt[N,K](bf16)^T (+bias f32)(+resid f32)
// ---------------------------------------------------------------------------
__global__ __launch_bounds__(256) void gemm_bf16_kernel(
    const ushort_t* __restrict__ A, const ushort_t* __restrict__ Wt,
    const float* __restrict__ bias, const float* __restrict__ resid,
    float* __restrict__ Cf, ushort_t* __restrict__ Cb,
    int M, int N, int K)
{
    __shared__ __align__(16) ushort_t As[64][72];
    __shared__ __align__(16) ushort_t Bs[64][72];
    int tid = threadIdx.x;
    int wave = tid >> 6, l15 = tid & 15, quad = (tid & 63) >> 4;
    int m0 = blockIdx.x * 64, n0 = blockIdx.y * 64;
    floatx4 acc[4] = {};

    for (int k0 = 0; k0 < K; k0 += 64) {
#pragma unroll
        for (int p = 0; p < 2; p++) {
            int lin = p * 256 + tid;
            int r = lin >> 3, c8 = (lin & 7) * 8;
            int m = m0 + r;
            short8 av = {};
            if (m < M) av = *(const short8*)&A[(size_t)m * K + k0 + c8];
            *(short8*)&As[r][c8] = av;
            *(short8*)&Bs[r][c8] = *(const short8*)&Wt[(size_t)(n0 + r) * K + k0 + c8];
        }
        __syncthreads();
        short8 a0 = *(const short8*)&As[16 * wave + l15][quad * 8];
        short8 a1 = *(const short8*)&As[16 * wave + l15][32 + quad * 8];
#pragma unroll
        for (int t = 0; t < 4; t++) {
            short8 b0 = *(const short8*)&Bs[16 * t + l15][quad * 8];
            short8 b1 = *(const short8*)&Bs[16 * t + l15][32 + quad * 8];
            acc[t] = __builtin_amdgcn_mfma_f32_16x16x32_bf16(a0, b0, acc[t], 0, 0, 0);
            acc[t] = __builtin_amdgcn_mfma_f32_16x16x32_bf16(a1, b1, acc[t], 0, 0, 0);
        }
        __syncthreads();
    }

    int mrow = m0 + 16 * wave + quad * 4;
#pragma unroll
    for (int t = 0; t < 4; t++) {
        int n = n0 + 16 * t + l15;
        float bv = bias ? bias[n] : 0.f;
#pragma unroll
        for (int i = 0; i < 4; i++) {
            int m = mrow + i;
            if (m < M) {
                float v = acc[t][i] + bv;
                if (resid) v += resid[(size_t)m * N + n];
                if (Cf) Cf[(size_t)m * N + n] = v;
                if (Cb) Cb[(size_t)m * N + n] = f2bf(v);
            }
        }
    }
}

// ---------------------------------------------------------------------------
// fc0 + GEGLU fused MFMA GEMM.
// ---------------------------------------------------------------------------
__global__ __launch_bounds__(256) void gemm_geglu_bf16_kernel(
    const ushort_t* __restrict__ A, const ushort_t* __restrict__ Wt,
    const float* __restrict__ bias, ushort_t* __restrict__ C, int M)
{
    constexpr int K = 320;
    __shared__ __align__(16) ushort_t As[64][72];
    __shared__ __align__(16) ushort_t Bv[64][72];
    __shared__ __align__(16) ushort_t Bg[64][72];
    int tid = threadIdx.x;
    int wave = tid >> 6, l15 = tid & 15, quad = (tid & 63) >> 4;
    int m0 = blockIdx.x * 64, n0 = blockIdx.y * 64;
    floatx4 av[4] = {}, ag[4] = {};

    for (int k0 = 0; k0 < K; k0 += 64) {
#pragma unroll
        for (int p = 0; p < 2; p++) {
            int lin = p * 256 + tid;
            int r = lin >> 3, c8 = (lin & 7) * 8;
            *(short8*)&As[r][c8] = *(const short8*)&A[(size_t)(m0 + r) * K + k0 + c8];
            *(short8*)&Bv[r][c8] = *(const short8*)&Wt[(size_t)(n0 + r) * K + k0 + c8];
            *(short8*)&Bg[r][c8] = *(const short8*)&Wt[(size_t)(FF + n0 + r) * K + k0 + c8];
        }
        __syncthreads();
        short8 a0 = *(const short8*)&As[16 * wave + l15][quad * 8];
        short8 a1 = *(const short8*)&As[16 * wave + l15][32 + quad * 8];
#pragma unroll
        for (int t = 0; t < 4; t++) {
            short8 b0 = *(const short8*)&Bv[16 * t + l15][quad * 8];
            short8 b1 = *(const short8*)&Bv[16 * t + l15][32 + quad * 8];
            av[t] = __builtin_amdgcn_mfma_f32_16x16x32_bf16(a0, b0, av[t], 0, 0, 0);
            av[t] = __builtin_amdgcn_mfma_f32_16x16x32_bf16(a1, b1, av[t], 0, 0, 0);
            short8 g0 = *(const short8*)&Bg[16 * t + l15][quad * 8];
            short8 g1 = *(const short8*)&Bg[16 * t + l15][32 + quad * 8];
            ag[t] = __builtin_amdgcn_mfma_f32_16x16x32_bf16(a0, g0, ag[t], 0, 0, 0);
            ag[t] = __builtin_amdgcn_mfma_f32_16x16x32_bf16(a1, g1, ag[t], 0, 0, 0);
        }
        __syncthreads();
    }

    int mrow = m0 + 16 * wave + quad * 4;
#pragma unroll
    for (int t = 0; t < 4; t++) {
        int n = n0 + 16 * t + l15;
        float bv = bias[n], bg = bias[FF + n];
#pragma unroll
        for (int i = 0; i < 4; i++) {
            int m = mrow + i;
            float val  = av[t][i] + bv;
            float gate = ag[t][i] + bg;
            float g = 0.5f * gate * (1.f + erff(gate * 0.70710678118654752f));
            C[(size_t)m * FF + n] = f2bf(val * g);
        }
    }
}

// ---------------------------------------------------------------------------
// MFMA flash attention v2: grid (L/128, H, B), 256 threads = 4 waves.
// Chunk-major LDS (dh=40 = 5 short8 chunks; k-pad chunks zeroed once).
// Vectorized staging: 320 b128 load+store pairs per k-tile.
// Wave w owns q-rows [32w,32w+32) as two 16-row C/D groups.
// ---------------------------------------------------------------------------
__global__ __launch_bounds__(256) void flash_mfma_kernel(
    const ushort_t* __restrict__ Qg, const ushort_t* __restrict__ Kg,
    const ushort_t* __restrict__ Vg, ushort_t* __restrict__ Og,
    int sQ, int sKV, int nk)
{
    __shared__ __align__(16) ushort_t Qs[8][TQ][8];    // [k-chunk][row][k%8], 16 KB
    __shared__ __align__(16) ushort_t Ks[8][64][8];    // 8 KB
    __shared__ __align__(16) ushort_t VsT[48][72];     // [dh][key], 6.75 KB
    __shared__ __align__(16) ushort_t Ps[8][130][8];   // [k-chunk][row][k%8], 16.6 KB

    int tid = threadIdx.x;
    int wave = tid >> 6, l15 = tid & 15, quad = (tid & 63) >> 4;
    int q0 = blockIdx.x * TQ, h = blockIdx.y, b = blockIdx.z;

    const ushort_t* Qb = Qg + (size_t)(b * SPATIAL + q0) * sQ + h * DH;
    const ushort_t* Kb = Kg + (size_t)b * nk * sKV + h * DH;
    const ushort_t* Vb = Vg + (size_t)b * nk * sKV + h * DH;

    const short8 z8 = {};
    // zero pads ONCE: Qs/Ks k-chunks 5..7 (k=40..63), VsT dh rows 40..47
    for (int i = tid; i < 3 * 64; i += 256)
        *(short8*)&Ks[5 + (i >> 6)][i & 63][0] = z8;
    for (int i = tid; i < 3 * TQ; i += 256)
        *(short8*)&Qs[5 + i / TQ][i % TQ][0] = z8;
    for (int i = tid; i < 8 * 72; i += 256)
        VsT[40 + i / 72][i % 72] = 0;
    // stage Q: 128 rows x 5 chunks, vector
    for (int t = tid; t < 5 * TQ; t += 256) {
        int row = t & (TQ - 1), cid = t >> 7;
        *(short8*)&Qs[cid][row][0] = *(const short8*)&Qb[(size_t)row * sQ + cid * 8];
    }
    __syncthreads();

    short8 aq[2][2];
#pragma unroll
    for (int g = 0; g < 2; g++) {
        int r = 32 * wave + 16 * g + l15;
        aq[g][0] = *(const short8*)&Qs[quad][r][0];
        aq[g][1] = *(const short8*)&Qs[4 + quad][r][0];
    }

    const float scale = 0.15811388300841897f;  // 1/sqrt(40)
    float mrow[2][4], lrow[2][4];
#pragma unroll
    for (int g = 0; g < 2; g++)
#pragma unroll
        for (int i = 0; i < 4; i++) { mrow[g][i] = -1e30f; lrow[g][i] = 0.f; }
    floatx4 o[2][3] = {};

    int ntiles = (nk + 63) >> 6;
    for (int t = 0; t < ntiles; t++) {
        int k0 = t * 64;
        __syncthreads();   // protect Ks/VsT from previous iteration readers
        // stage K (chunk-major) + V (transposed, lane-contiguous): 320 vec tasks
        for (int tk = tid; tk < 320; tk += 256) {
            int row = tk & 63, cid = tk >> 6;
            size_t goff = (size_t)(k0 + row) * sKV + cid * 8;
            short8 k8 = *(const short8*)&Kb[goff];
            *(short8*)&Ks[cid][row][0] = k8;
            short8 v8 = *(const short8*)&Vb[goff];
#pragma unroll
            for (int j = 0; j < 8; j++) VsT[cid * 8 + j][row] = v8[j];
        }
        __syncthreads();

        // S = Q K^T for both row-groups, sharing B-fragment reads
        floatx4 s[2][4] = {};
#pragma unroll
        for (int tt = 0; tt < 4; tt++) {
            short8 b0 = *(const short8*)&Ks[quad][16 * tt + l15][0];
            short8 b1 = *(const short8*)&Ks[4 + quad][16 * tt + l15][0];
#pragma unroll
            for (int g = 0; g < 2; g++) {
                s[g][tt] = __builtin_amdgcn_mfma_f32_16x16x32_bf16(aq[g][0], b0, s[g][tt], 0, 0, 0);
                s[g][tt] = __builtin_amdgcn_mfma_f32_16x16x32_bf16(aq[g][1], b1, s[g][tt], 0, 0, 0);
            }
        }

        // online softmax (per row-group, per reg-row); Ps write in A-layout
        bool full = (k0 + 64 <= nk);
#pragma unroll
        for (int g = 0; g < 2; g++) {
#pragma unroll
            for (int i = 0; i < 4; i++) {
                float sv[4];
#pragma unroll
                for (int tt = 0; tt < 4; tt++) {
                    int col = k0 + 16 * tt + l15;
                    float x = s[g][tt][i] * scale;
                    sv[tt] = (full || col < nk) ? x : -1e30f;
                }
                float mx = fmaxf(fmaxf(sv[0], sv[1]), fmaxf(sv[2], sv[3]));
#pragma unroll
                for (int msk = 1; msk < 16; msk <<= 1) mx = fmaxf(mx, __shfl_xor(mx, msk));
                float mn = fmaxf(mrow[g][i], mx);
                float al = __expf(mrow[g][i] - mn);
                mrow[g][i] = mn;
                int row = 32 * wave + 16 * g + 4 * quad + i;
                float rs = 0.f;
#pragma unroll
                for (int tt = 0; tt < 4; tt++) {
                    float pv = __expf(sv[tt] - mn);
                    Ps[2 * tt + (l15 >> 3)][row][l15 & 7] = f2bf(pv);
                    rs += pv;
                }
#pragma unroll
                for (int msk = 1; msk < 16; msk <<= 1) rs += __shfl_xor(rs, msk);
                lrow[g][i] = lrow[g][i] * al + rs;
#pragma unroll
                for (int t2 = 0; t2 < 3; t2++) o[g][t2][i] *= al;
            }
        }

        // PV: O += P @ V. V B-fragments shared across row-groups.
        short8 vb[3][2];
#pragma unroll
        for (int t2 = 0; t2 < 3; t2++) {
            vb[t2][0] = *(const short8*)&VsT[16 * t2 + l15][quad * 8];
            vb[t2][1] = *(const short8*)&VsT[16 * t2 + l15][32 + quad * 8];
        }
#pragma unroll
        for (int g = 0; g < 2; g++) {
            int r = 32 * wave + 16 * g + l15;
            short8 p0 = *(const short8*)&Ps[quad][r][0];
            short8 p1 = *(const short8*)&Ps[4 + quad][r][0];
#pragma unroll
            for (int t2 = 0; t2 < 3; t2++) {
                o[g][t2] = __builtin_amdgcn_mfma_f32_16x16x32_bf16(p0, vb[t2][0], o[g][t2], 0, 0, 0);
                o[g][t2] = __builtin_amdgcn_mfma_f32_16x16x32_bf16(p1, vb[t2][1], o[g][t2], 0, 0, 0);
            }
        }
    }

#pragma unroll
    for (int g = 0; g < 2; g++) {
        float inv[4];
#pragma unroll
        for (int i = 0; i < 4; i++) inv[i] = 1.f / lrow[g][i];
#pragma unroll
        for (int t2 = 0; t2 < 3; t2++) {
            int c = 16 * t2 + l15;
            if (c < DH) {
#pragma unroll
                for (int i = 0; i < 4; i++) {
                    size_t row = (size_t)(b * SPATIAL + q0 + 32 * wave + 16 * g + 4 * quad + i);
                    Og[row * DIM + h * DH + c] = f2bf(o[g][t2][i] * inv[i]);
                }
            }
        }
    }
}

// ---------------------------------------------------------------------------
extern "C" void kernel_launch(void* const* d_in, const int* in_sizes, int n_in,
                              void* d_out, int out_size, void* d_ws, size_t ws_size,
                              hipStream_t stream) {
    (void)in_sizes; (void)n_in; (void)out_size; (void)ws_size;
    const float* q      = (const float*)d_in[0];
    const float* kv     = (const float*)d_in[1];
    const float* gn_s   = (const float*)d_in[2];
    const float* gn_b   = (const float*)d_in[3];
    const float* cin_w  = (const float*)d_in[4];
    const float* cin_b  = (const float*)d_in[5];
    const float* ln0_s  = (const float*)d_in[6];
    const float* ln0_b  = (const float*)d_in[7];
    const float* a1_wq  = (const float*)d_in[8];
    const float* a1_wk  = (const float*)d_in[9];
    const float* a1_wv  = (const float*)d_in[10];
    const float* a1_wo  = (const float*)d_in[11];
    const float* a1_bo  = (const float*)d_in[12];
    const float* ln1_s  = (const float*)d_in[13];
    const float* ln1_b  = (const float*)d_in[14];
    const float* a2_wq  = (const float*)d_in[15];
    const float* a2_wk  = (const float*)d_in[16];
    const float* a2_wv  = (const float*)d_in[17];
    const float* a2_wo  = (const float*)d_in[18];
    const float* a2_bo  = (const float*)d_in[19];
    const float* lnA_s  = (const float*)d_in[20];
    const float* lnA_b  = (const float*)d_in[21];
    const float* fc0_w  = (const float*)d_in[22];
    const float* fc0_b  = (const float*)d_in[23];
    const float* fc1_w  = (const float*)d_in[24];
    const float* fc1_b  = (const float*)d_in[25];
    const float* cout_w = (const float*)d_in[26];
    const float* cout_b = (const float*)d_in[27];
    float* out = (float*)d_out;

    // ---- workspace carve ----
    char* p = (char*)d_ws;
    auto carve = [&](size_t bytes) -> char* {
        char* r = p;
        p += (bytes + 255) & ~(size_t)255;
        return r;
    };
    float*    stats  = (float*)carve(512);
    float*    B0     = (float*)carve((size_t)ROWS * DIM * 4);
    float*    B2     = (float*)carve((size_t)ROWS * DIM * 4);
    ushort_t* gnO    = (ushort_t*)carve((size_t)ROWS * DIM * 2);
    ushort_t* ln0O   = (ushort_t*)carve((size_t)ROWS * DIM * 2);
    ushort_t* QKV    = (ushort_t*)carve((size_t)ROWS * 960 * 2);
    ushort_t* attnO  = (ushort_t*)carve((size_t)ROWS * DIM * 2);
    ushort_t* ln1O   = (ushort_t*)carve((size_t)ROWS * DIM * 2);
    ushort_t* Q2     = (ushort_t*)carve((size_t)ROWS * DIM * 2);
    ushort_t* KVc    = (ushort_t*)carve((size_t)BATCH * KVL * 640 * 2);
    ushort_t* lnAO   = (ushort_t*)carve((size_t)ROWS * DIM * 2);
    ushort_t* GLU    = (ushort_t*)carve((size_t)ROWS * FF * 2);
    ushort_t* X2     = (ushort_t*)carve((size_t)ROWS * DIM * 2);
    ushort_t* kvbf   = (ushort_t*)carve((size_t)BATCH * KVL * KVD * 2);
    ushort_t* qkv_t  = (ushort_t*)carve((size_t)960 * 320 * 2);
    ushort_t* cin_t  = (ushort_t*)carve((size_t)320 * 320 * 2);
    ushort_t* a1wo_t = (ushort_t*)carve((size_t)320 * 320 * 2);
    ushort_t* a2wq_t = (ushort_t*)carve((size_t)320 * 320 * 2);
    ushort_t* kvx_t  = (ushort_t*)carve((size_t)640 * 768 * 2);
    ushort_t* a2wo_t = (ushort_t*)carve((size_t)320 * 320 * 2);
    ushort_t* fc0_t  = (ushort_t*)carve((size_t)2560 * 320 * 2);
    ushort_t* fc1_t  = (ushort_t*)carve((size_t)320 * 1280 * 2);
    ushort_t* cout_t = (ushort_t*)carve((size_t)320 * 320 * 2);

    dim3 b32(32, 32);
    auto wtrans = [&](const float* src, ushort_t* dst, int K, int N) {
        wtrans_kernel<<<dim3(N / 32, K / 32), b32, 0, stream>>>(src, dst, K, N);
    };
    auto gemm = [&](const ushort_t* A, const ushort_t* Wt, const float* bias,
                    const float* resid, float* Cf, ushort_t* Cb, int M, int N, int K) {
        gemm_bf16_kernel<<<dim3((M + 63) / 64, N / 64), 256, 0, stream>>>(
            A, Wt, bias, resid, Cf, Cb, M, N, K);
    };

    // ---- weight prep ----
    wtrans(cin_w,  cin_t,  320, 320);
    wtrans(a1_wq,  qkv_t,              320, 320);
    wtrans(a1_wk,  qkv_t + 320 * 320,  320, 320);
    wtrans(a1_wv,  qkv_t + 640 * 320,  320, 320);
    wtrans(a1_wo,  a1wo_t, 320, 320);
    wtrans(a2_wq,  a2wq_t, 320, 320);
    wtrans(a2_wk,  kvx_t,              768, 320);
    wtrans(a2_wv,  kvx_t + 320 * 768,  768, 320);
    wtrans(a2_wo,  a2wo_t, 320, 320);
    wtrans(fc0_w,  fc0_t,  320, 2560);
    wtrans(fc1_w,  fc1_t,  1280, 320);
    wtrans(cout_w, cout_t, 320, 320);
    {
        int n = BATCH * KVL * KVD;
        cvt_bf16_kernel<<<(n + 255) / 256, 256, 0, stream>>>(kv, kvbf, n);
    }

    // ---- GroupNorm + conv_in ----
    zero_stats_kernel<<<1, 128, 0, stream>>>(stats);
    gn_partial_kernel<<<dim3(16, 64), 256, 0, stream>>>(q, stats);
    gn_apply_transpose_kernel<<<dim3(SPATIAL / 32, DIM / 32, BATCH), b32, 0, stream>>>(
        q, stats, gn_s, gn_b, gnO);
    gemm(gnO, cin_t, cin_b, nullptr, B0, nullptr, ROWS, DIM, DIM);

    // ---- self-attention ----
    ln_kernel<<<ROWS, 64, 0, stream>>>(B0, ln0_s, ln0_b, ln0O);
    gemm(ln0O, qkv_t, nullptr, nullptr, nullptr, QKV, ROWS, 960, DIM);
    flash_mfma_kernel<<<dim3(SPATIAL / TQ, NHEADS, BATCH), 256, 0, stream>>>(
        QKV, QKV + 320, QKV + 640, attnO, 960, 960, SPATIAL);
    gemm(attnO, a1wo_t, a1_bo, B0, B0, nullptr, ROWS, DIM, DIM);

    // ---- cross-attention ----
    ln_kernel<<<ROWS, 64, 0, stream>>>(B0, ln1_s, ln1_b, ln1O);
    gemm(ln1O, a2wq_t, nullptr, nullptr, nullptr, Q2, ROWS, DIM, DIM);
    gemm(kvbf, kvx_t, nullptr, nullptr, nullptr, KVc, BATCH * KVL, 640, KVD);
    flash_mfma_kernel<<<dim3(SPATIAL / TQ, NHEADS, BATCH), 256, 0, stream>>>(
        Q2, KVc, KVc + 320, attnO, 320, 640, KVL);
    gemm(attnO, a2wo_t, a2_bo, B0, B0, nullptr, ROWS, DIM, DIM);

    // ---- FFN (GEGLU) ----
    ln_kernel<<<ROWS, 64, 0, stream>>>(B0, lnA_s, lnA_b, lnAO);
    gemm_geglu_bf16_kernel<<<dim3(ROWS / 64, FF / 64), 256, 0, stream>>>(
        lnAO, fc0_t, fc0_b, GLU, ROWS);
    gemm(GLU, fc1_t, fc1_b, B0, nullptr, X2, ROWS, DIM, FF);

    // ---- conv_out + res1 ----
    gemm(X2, cout_t, cout_b, nullptr, B2, nullptr, ROWS, DIM, DIM);
    out_transpose_kernel<<<dim3(SPATIAL / 32, DIM / 32, BATCH), b32, 0, stream>>>(B2, q, out);
}

// Round 5
// 430.934 us; speedup vs baseline: 25.2208x; 1.3195x over previous
//
#include <hip/hip_runtime.h>
#include <math.h>

typedef short short8 __attribute__((ext_vector_type(8)));
typedef float floatx4 __attribute__((ext_vector_type(4)));
typedef unsigned short ushort_t;
typedef unsigned int uint_t;

// ---- problem constants ----
constexpr int BATCH   = 2;
constexpr int DIM     = 320;
constexpr int NHEADS  = 8;
constexpr int DH      = 40;
constexpr int NGROUPS = 32;
constexpr int CPG     = 10;
constexpr int SPATIAL = 4096;
constexpr int ROWS    = BATCH * SPATIAL;   // 8192
constexpr int KVL     = 77;
constexpr int KVD     = 768;
constexpr int FF      = 1280;              // geglu half width
constexpr int TQ      = 128;               // flash q-tile

// scale(1/sqrt(40)) * log2(e): folded into Q so flash uses exp2 directly
#define QK_EXP2_SCALE 0.2281259062f

__device__ __forceinline__ ushort_t f2bf(float f) {
    uint_t u = __float_as_uint(f);
    u += 0x7FFFu + ((u >> 16) & 1u);       // RNE
    return (ushort_t)(u >> 16);
}

// async global->LDS, 16B per lane; LDS dest = wave-uniform base + lane*16
__device__ __forceinline__ void gld16(const ushort_t* g, ushort_t* l) {
    __builtin_amdgcn_global_load_lds(
        (const __attribute__((address_space(1))) void*)g,
        (__attribute__((address_space(3))) void*)l, 16, 0, 0);
}

// ---------------------------------------------------------------------------
__global__ void zero_stats_kernel(float* stats) {
    if (threadIdx.x < 128) stats[threadIdx.x] = 0.f;
}

__global__ __launch_bounds__(256) void gn_partial_kernel(const float* __restrict__ q,
                                                         float* __restrict__ stats) {
    int slice = blockIdx.x, bg = blockIdx.y;
    const float* base = q + (size_t)bg * (CPG * SPATIAL) + slice * 2560;
    float s = 0.f, ss = 0.f;
#pragma unroll
    for (int j = 0; j < 10; j++) {
        float v = base[j * 256 + threadIdx.x];
        s += v; ss += v * v;
    }
    __shared__ float rs[256], rss[256];
    rs[threadIdx.x] = s; rss[threadIdx.x] = ss;
    __syncthreads();
    for (int off = 128; off > 0; off >>= 1) {
        if (threadIdx.x < off) {
            rs[threadIdx.x]  += rs[threadIdx.x + off];
            rss[threadIdx.x] += rss[threadIdx.x + off];
        }
        __syncthreads();
    }
    if (threadIdx.x == 0) {
        atomicAdd(&stats[bg * 2],     rs[0]);
        atomicAdd(&stats[bg * 2 + 1], rss[0]);
    }
}

__global__ void gn_apply_transpose_kernel(const float* __restrict__ q,
                                          const float* __restrict__ stats,
                                          const float* __restrict__ gs,
                                          const float* __restrict__ gb,
                                          ushort_t* __restrict__ out) {
    __shared__ float tile[32][33];
    int l0 = blockIdx.x * 32, c0 = blockIdx.y * 32, b = blockIdx.z;
    int tx = threadIdx.x, ty = threadIdx.y;
    int c = c0 + ty;
    int g = c / CPG;
    float s  = stats[(b * NGROUPS + g) * 2];
    float ss = stats[(b * NGROUPS + g) * 2 + 1];
    const float invn = 1.f / 40960.f;
    float mean = s * invn;
    float rstd = rsqrtf(ss * invn - mean * mean + 1e-6f);
    float v = q[((size_t)(b * DIM + c)) * SPATIAL + l0 + tx];
    tile[ty][tx] = (v - mean) * rstd * gs[c] + gb[c];
    __syncthreads();
    out[((size_t)(b * SPATIAL + l0 + ty)) * DIM + c0 + tx] = f2bf(tile[tx][ty]);
}

__global__ void out_transpose_kernel(const float* __restrict__ xin,
                                     const float* __restrict__ q,
                                     float* __restrict__ out) {
    __shared__ float tile[32][33];
    int l0 = blockIdx.x * 32, c0 = blockIdx.y * 32, b = blockIdx.z;
    int tx = threadIdx.x, ty = threadIdx.y;
    tile[ty][tx] = xin[((size_t)(b * SPATIAL + l0 + ty)) * DIM + c0 + tx];
    __syncthreads();
    size_t oi = ((size_t)(b * DIM + c0 + ty)) * SPATIAL + l0 + tx;
    out[oi] = tile[tx][ty] + q[oi];
}

__global__ __launch_bounds__(64) void ln_kernel(const float* __restrict__ x,
                                                const float* __restrict__ sc,
                                                const float* __restrict__ bi,
                                                ushort_t* __restrict__ out) {
    int row = blockIdx.x;
    const float* xr = x + (size_t)row * DIM;
    float v[5];
    float sum = 0.f, sq = 0.f;
#pragma unroll
    for (int j = 0; j < 5; j++) {
        v[j] = xr[threadIdx.x + j * 64];
        sum += v[j]; sq += v[j] * v[j];
    }
#pragma unroll
    for (int off = 32; off > 0; off >>= 1) {
        sum += __shfl_down(sum, off);
        sq  += __shfl_down(sq, off);
    }
    sum = __shfl(sum, 0); sq = __shfl(sq, 0);
    float mean = sum / (float)DIM;
    float rstd = rsqrtf(sq / (float)DIM - mean * mean + 1e-5f);
#pragma unroll
    for (int j = 0; j < 5; j++) {
        int i = threadIdx.x + j * 64;
        out[(size_t)row * DIM + i] = f2bf((v[j] - mean) * rstd * sc[i] + bi[i]);
    }
}

// ---------------------------------------------------------------------------
// All weight transposes fused: f32 [K][N] -> bf16 [N][K], 12 segments.
// ---------------------------------------------------------------------------
struct WSeg { const float* src; ushort_t* dst; int K; int N; int t0; };
struct WTab { WSeg s[12]; };

__global__ __launch_bounds__(256) void wtrans_all_kernel(WTab tab) {
    __shared__ float tile[32][33];
    int bid = blockIdx.x;
    int si = 0;
#pragma unroll
    for (int i = 1; i < 12; i++) if (bid >= tab.s[i].t0) si = i;
    WSeg sg = tab.s[si];
    int local = bid - sg.t0;
    int ntn = sg.N >> 5;
    int kt = local / ntn, nt = local - kt * ntn;
    int n0 = nt * 32, k0 = kt * 32;
    int tx = threadIdx.x & 31, ty8 = threadIdx.x >> 5;
    for (int r = ty8; r < 32; r += 8)
        tile[r][tx] = sg.src[(size_t)(k0 + r) * sg.N + n0 + tx];
    __syncthreads();
    for (int r = ty8; r < 32; r += 8)
        sg.dst[(size_t)(n0 + r) * sg.K + k0 + tx] = f2bf(tile[tx][r]);
}

__global__ void cvt_bf16_kernel(const float* __restrict__ src, ushort_t* __restrict__ dst, int n) {
    int i = blockIdx.x * 256 + threadIdx.x;
    if (i < n) dst[i] = f2bf(src[i]);
}

// ---------------------------------------------------------------------------
// m97-style bf16 MFMA GEMM: tile 128(M) x 64(N) x 64(K), global_load_lds,
// XOR-swizzled unpadded LDS. C = A[M,K] @ Wt[N,K]^T (+bias)(+resid).
// Optional column scale for n < ncut (folds softmax scale into Q).
// M % 128 == 0, N % 64 == 0, K % 64 == 0 at all call sites.
// ---------------------------------------------------------------------------
__global__ __launch_bounds__(256) void gemm128_kernel(
    const ushort_t* __restrict__ A, const ushort_t* __restrict__ Wt,
    const float* __restrict__ bias, const float* __restrict__ resid,
    float* __restrict__ Cf, ushort_t* __restrict__ Cb,
    int M, int N, int K, float qsc, int ncut)
{
    __shared__ __align__(16) ushort_t As[128][64];
    __shared__ __align__(16) ushort_t Bs[64][64];
    int tid = threadIdx.x;
    int wave = tid >> 6, lane = tid & 63;
    int l15 = tid & 15, quad = lane >> 4;
    int m0 = blockIdx.x * 128, n0 = blockIdx.y * 64;
    int lrow = lane >> 3, slot = lane & 7;
    floatx4 acc[2][4] = {};

    for (int k0 = 0; k0 < K; k0 += 64) {
#pragma unroll
        for (int t = 0; t < 4; t++) {
            int task = wave * 4 + t;
            int r = task * 8 + lrow;
            int gc = slot ^ (r & 7);
            gld16(&A[(size_t)(m0 + r) * K + k0 + gc * 8], &As[task * 8][0]);
        }
#pragma unroll
        for (int t = 0; t < 2; t++) {
            int task = wave * 2 + t;
            int r = task * 8 + lrow;
            int gc = slot ^ (r & 7);
            gld16(&Wt[(size_t)(n0 + r) * K + k0 + gc * 8], &Bs[task * 8][0]);
        }
        __syncthreads();
        short8 a[2][2], b[4][2];
#pragma unroll
        for (int g = 0; g < 2; g++) {
            int r = 32 * wave + 16 * g + l15;
            a[g][0] = *(const short8*)&As[r][(quad ^ (r & 7)) * 8];
            a[g][1] = *(const short8*)&As[r][((4 + quad) ^ (r & 7)) * 8];
        }
#pragma unroll
        for (int t = 0; t < 4; t++) {
            int r = 16 * t + l15;
            b[t][0] = *(const short8*)&Bs[r][(quad ^ (r & 7)) * 8];
            b[t][1] = *(const short8*)&Bs[r][((4 + quad) ^ (r & 7)) * 8];
        }
#pragma unroll
        for (int g = 0; g < 2; g++)
#pragma unroll
            for (int t = 0; t < 4; t++) {
                acc[g][t] = __builtin_amdgcn_mfma_f32_16x16x32_bf16(a[g][0], b[t][0], acc[g][t], 0, 0, 0);
                acc[g][t] = __builtin_amdgcn_mfma_f32_16x16x32_bf16(a[g][1], b[t][1], acc[g][t], 0, 0, 0);
            }
        __syncthreads();
    }

#pragma unroll
    for (int g = 0; g < 2; g++) {
        int mrow = m0 + 32 * wave + 16 * g + quad * 4;
#pragma unroll
        for (int t = 0; t < 4; t++) {
            int n = n0 + 16 * t + l15;
            float bv = bias ? bias[n] : 0.f;
            float sc = (n < ncut) ? qsc : 1.f;
#pragma unroll
            for (int i = 0; i < 4; i++) {
                int m = mrow + i;
                float v = acc[g][t][i] + bv;
                if (resid) v += resid[(size_t)m * N + n];
                v *= sc;
                if (Cf) Cf[(size_t)m * N + n] = v;
                if (Cb) Cb[(size_t)m * N + n] = f2bf(v);
            }
        }
    }
}

// ---------------------------------------------------------------------------
// fc0+GEGLU on the gemm128 structure: dual B (value cols n0.., gate FF+n0..)
// ---------------------------------------------------------------------------
__global__ __launch_bounds__(256) void geglu128_kernel(
    const ushort_t* __restrict__ A, const ushort_t* __restrict__ Wt,
    const float* __restrict__ bias, ushort_t* __restrict__ C, int M)
{
    constexpr int K = 320;
    __shared__ __align__(16) ushort_t As[128][64];
    __shared__ __align__(16) ushort_t Bv[64][64];
    __shared__ __align__(16) ushort_t Bg[64][64];
    int tid = threadIdx.x;
    int wave = tid >> 6, lane = tid & 63;
    int l15 = tid & 15, quad = lane >> 4;
    int m0 = blockIdx.x * 128, n0 = blockIdx.y * 64;
    int lrow = lane >> 3, slot = lane & 7;
    floatx4 av[2][4] = {}, ag[2][4] = {};

    for (int k0 = 0; k0 < K; k0 += 64) {
#pragma unroll
        for (int t = 0; t < 4; t++) {
            int task = wave * 4 + t;
            int r = task * 8 + lrow;
            int gc = slot ^ (r & 7);
            gld16(&A[(size_t)(m0 + r) * K + k0 + gc * 8], &As[task * 8][0]);
        }
#pragma unroll
        for (int t = 0; t < 2; t++) {
            int task = wave * 2 + t;
            int r = task * 8 + lrow;
            int gc = slot ^ (r & 7);
            gld16(&Wt[(size_t)(n0 + r) * K + k0 + gc * 8],        &Bv[task * 8][0]);
            gld16(&Wt[(size_t)(FF + n0 + r) * K + k0 + gc * 8],   &Bg[task * 8][0]);
        }
        __syncthreads();
        short8 a[2][2], bv[4][2], bg[4][2];
#pragma unroll
        for (int g = 0; g < 2; g++) {
            int r = 32 * wave + 16 * g + l15;
            a[g][0] = *(const short8*)&As[r][(quad ^ (r & 7)) * 8];
            a[g][1] = *(const short8*)&As[r][((4 + quad) ^ (r & 7)) * 8];
        }
#pragma unroll
        for (int t = 0; t < 4; t++) {
            int r = 16 * t + l15;
            bv[t][0] = *(const short8*)&Bv[r][(quad ^ (r & 7)) * 8];
            bv[t][1] = *(const short8*)&Bv[r][((4 + quad) ^ (r & 7)) * 8];
            bg[t][0] = *(const short8*)&Bg[r][(quad ^ (r & 7)) * 8];
            bg[t][1] = *(const short8*)&Bg[r][((4 + quad) ^ (r & 7)) * 8];
        }
#pragma unroll
        for (int g = 0; g < 2; g++)
#pragma unroll
            for (int t = 0; t < 4; t++) {
                av[g][t] = __builtin_amdgcn_mfma_f32_16x16x32_bf16(a[g][0], bv[t][0], av[g][t], 0, 0, 0);
                av[g][t] = __builtin_amdgcn_mfma_f32_16x16x32_bf16(a[g][1], bv[t][1], av[g][t], 0, 0, 0);
                ag[g][t] = __builtin_amdgcn_mfma_f32_16x16x32_bf16(a[g][0], bg[t][0], ag[g][t], 0, 0, 0);
                ag[g][t] = __builtin_amdgcn_mfma_f32_16x16x32_bf16(a[g][1], bg[t][1], ag[g][t], 0, 0, 0);
            }
        __syncthreads();
    }

#pragma unroll
    for (int g = 0; g < 2; g++) {
        int mrow = m0 + 32 * wave + 16 * g + quad * 4;
#pragma unroll
        for (int t = 0; t < 4; t++) {
            int n = n0 + 16 * t + l15;
            float bb = bias[n], bgte = bias[FF + n];
#pragma unroll
            for (int i = 0; i < 4; i++) {
                float val  = av[g][t][i] + bb;
                float gate = ag[g][t][i] + bgte;
                float gl = 0.5f * gate * (1.f + erff(gate * 0.70710678118654752f));
                C[(size_t)(mrow + i) * FF + n] = f2bf(val * gl);
            }
        }
    }
}

// ---------------------------------------------------------------------------
// Small-M bf16 GEMM (cross K/V projection, M=154). R4-validated path.
// ---------------------------------------------------------------------------
__global__ __launch_bounds__(256) void gemm_small_kernel(
    const ushort_t* __restrict__ A, const ushort_t* __restrict__ Wt,
    ushort_t* __restrict__ Cb, int M, int N, int K)
{
    __shared__ __align__(16) ushort_t As[64][72];
    __shared__ __align__(16) ushort_t Bs[64][72];
    int tid = threadIdx.x;
    int wave = tid >> 6, l15 = tid & 15, quad = (tid & 63) >> 4;
    int m0 = blockIdx.x * 64, n0 = blockIdx.y * 64;
    floatx4 acc[4] = {};

    for (int k0 = 0; k0 < K; k0 += 64) {
#pragma unroll
        for (int p = 0; p < 2; p++) {
            int lin = p * 256 + tid;
            int r = lin >> 3, c8 = (lin & 7) * 8;
            int m = m0 + r;
            short8 avv = {};
            if (m < M) avv = *(const short8*)&A[(size_t)m * K + k0 + c8];
            *(short8*)&As[r][c8] = avv;
            *(short8*)&Bs[r][c8] = *(const short8*)&Wt[(size_t)(n0 + r) * K + k0 + c8];
        }
        __syncthreads();
        short8 a0 = *(const short8*)&As[16 * wave + l15][quad * 8];
        short8 a1 = *(const short8*)&As[16 * wave + l15][32 + quad * 8];
#pragma unroll
        for (int t = 0; t < 4; t++) {
            short8 b0 = *(const short8*)&Bs[16 * t + l15][quad * 8];
            short8 b1 = *(const short8*)&Bs[16 * t + l15][32 + quad * 8];
            acc[t] = __builtin_amdgcn_mfma_f32_16x16x32_bf16(a0, b0, acc[t], 0, 0, 0);
            acc[t] = __builtin_amdgcn_mfma_f32_16x16x32_bf16(a1, b1, acc[t], 0, 0, 0);
        }
        __syncthreads();
    }
    int mrow = m0 + 16 * wave + quad * 4;
#pragma unroll
    for (int t = 0; t < 4; t++) {
        int n = n0 + 16 * t + l15;
#pragma unroll
        for (int i = 0; i < 4; i++) {
            int m = mrow + i;
            if (m < M) Cb[(size_t)m * N + n] = f2bf(acc[t][i]);
        }
    }
}

// ---------------------------------------------------------------------------
// Flash attention v3: reduction-free softmax (Q pre-scaled by scale*log2e in
// its GEMM epilogue; p = exp2(s); row-sum l via ones-column in V). Optional
// split-K over key range (NPARTS=2 writes f32 partials + l).
// grid (L/128, H, B*NPARTS), 256 threads = 4 waves; wave owns 32 q-rows.
// ---------------------------------------------------------------------------
template <int NPARTS>
__global__ __launch_bounds__(256) void flash_kernel(
    const ushort_t* __restrict__ Qg, const ushort_t* __restrict__ Kg,
    const ushort_t* __restrict__ Vg, ushort_t* __restrict__ Og,
    float* __restrict__ Opart, float* __restrict__ Lpart,
    int sQ, int sKV, int nk)
{
    __shared__ __align__(16) ushort_t QPs[8][130][8];   // Q (rows 0..127), then P
    __shared__ __align__(16) ushort_t Ks[8][64][8];
    __shared__ __align__(16) ushort_t VsT[48][72];      // [dh][key]; row 40 = ones

    int tid = threadIdx.x;
    int wave = tid >> 6, lane = tid & 63;
    int l15 = tid & 15, quad = lane >> 4;
    int qt = blockIdx.x, h = blockIdx.y;
    int b, kp;
    if (NPARTS == 2) { b = blockIdx.z >> 1; kp = blockIdx.z & 1; }
    else             { b = blockIdx.z;      kp = 0; }
    int q0 = qt * TQ;

    const ushort_t* Qb = Qg + (size_t)(b * SPATIAL + q0) * sQ + h * DH;
    const ushort_t* Kb = Kg + (size_t)b * nk * sKV + h * DH;
    const ushort_t* Vb = Vg + (size_t)b * nk * sKV + h * DH;

    // zero K pad chunks (k=40..63) and VsT pad rows; then ones-row at dh=40
    const short8 z8 = {};
    for (int i = tid; i < 3 * 64; i += 256)
        *(short8*)&Ks[5 + (i >> 6)][i & 63][0] = z8;
    for (int i = tid; i < 8 * 72; i += 256)
        VsT[40 + i / 72][i % 72] = 0;
    if (tid < 72) VsT[40][tid] = 0x3F80;               // bf16 1.0 (same threads as zero; ordered)

    // stage Q via global_load_lds: 10 wave-tasks of 64 rows x 16B
    for (int t5 = wave; t5 < 10; t5 += 4) {
        int cid = t5 >> 1, half = t5 & 1;
        gld16(&Qb[(size_t)(half * 64 + lane) * sQ + cid * 8], &QPs[cid][half * 64][0]);
    }
    __syncthreads();

    short8 aq[2][2];
#pragma unroll
    for (int g = 0; g < 2; g++) {
        int r = 32 * wave + 16 * g + l15;
        aq[g][0] = *(const short8*)&QPs[quad][r][0];
        aq[g][1] = *(const short8*)&QPs[4 + quad][r][0];
    }

    floatx4 o[2][3] = {};

    int ntiles_all = (nk + 63) >> 6;
    int t_lo = (NPARTS == 2) ? kp * (ntiles_all >> 1) : 0;
    int t_hi = (NPARTS == 2) ? t_lo + (ntiles_all >> 1) : ntiles_all;

    for (int t = t_lo; t < t_hi; t++) {
        int k0 = t * 64;
        __syncthreads();   // protect Ks/VsT (+Q-frag reads on first iter)
        // K: 5 direct-to-LDS wave-tasks (OOB rows land in ws; masked below)
        for (int c = wave; c < 5; c += 4)
            gld16(&Kb[(size_t)(k0 + lane) * sKV + c * 8], &Ks[c][0][0]);
        // V: vectorized transpose staging (guarded: 0 for invalid keys)
        for (int tk = tid; tk < 320; tk += 256) {
            int row = tk & 63, cid = tk >> 6;
            int kr = k0 + row;
            short8 v8 = z8;
            if (kr < nk) v8 = *(const short8*)&Vb[(size_t)kr * sKV + cid * 8];
#pragma unroll
            for (int j = 0; j < 8; j++) VsT[cid * 8 + j][row] = v8[j];
        }
        __syncthreads();

        // S' = (Q*scale*log2e) K^T
        floatx4 s[2][4] = {};
#pragma unroll
        for (int tt = 0; tt < 4; tt++) {
            short8 b0 = *(const short8*)&Ks[quad][16 * tt + l15][0];
            short8 b1 = *(const short8*)&Ks[4 + quad][16 * tt + l15][0];
#pragma unroll
            for (int g = 0; g < 2; g++) {
                s[g][tt] = __builtin_amdgcn_mfma_f32_16x16x32_bf16(aq[g][0], b0, s[g][tt], 0, 0, 0);
                s[g][tt] = __builtin_amdgcn_mfma_f32_16x16x32_bf16(aq[g][1], b1, s[g][tt], 0, 0, 0);
            }
        }

        // p = exp2(s'); store P (trunc-bf16) into A-layout; no reductions.
        bool full = (k0 + 64 <= nk);
#pragma unroll
        for (int g = 0; g < 2; g++) {
#pragma unroll
            for (int i = 0; i < 4; i++) {
                int row = 32 * wave + 16 * g + 4 * quad + i;
#pragma unroll
                for (int tt = 0; tt < 4; tt++) {
                    float x = s[g][tt][i];
                    if (!full && (k0 + 16 * tt + l15 >= nk)) x = -1e30f;
                    float pf = exp2f(x);
                    QPs[2 * tt + (l15 >> 3)][row][l15 & 7] =
                        (ushort_t)(__float_as_uint(pf) >> 16);
                }
            }
        }

        // O += P @ [V | 1]; col 40 accumulates l. P rows wave-private.
        short8 vb[3][2];
#pragma unroll
        for (int t2 = 0; t2 < 3; t2++) {
            vb[t2][0] = *(const short8*)&VsT[16 * t2 + l15][quad * 8];
            vb[t2][1] = *(const short8*)&VsT[16 * t2 + l15][32 + quad * 8];
        }
#pragma unroll
        for (int g = 0; g < 2; g++) {
            int r = 32 * wave + 16 * g + l15;
            short8 p0 = *(const short8*)&QPs[quad][r][0];
            short8 p1 = *(const short8*)&QPs[4 + quad][r][0];
#pragma unroll
            for (int t2 = 0; t2 < 3; t2++) {
                o[g][t2] = __builtin_amdgcn_mfma_f32_16x16x32_bf16(p0, vb[t2][0], o[g][t2], 0, 0, 0);
                o[g][t2] = __builtin_amdgcn_mfma_f32_16x16x32_bf16(p1, vb[t2][1], o[g][t2], 0, 0, 0);
            }
        }
    }

    if (NPARTS == 1) {
        float inv[2][4];
#pragma unroll
        for (int g = 0; g < 2; g++)
#pragma unroll
            for (int i = 0; i < 4; i++)
                inv[g][i] = 1.f / __shfl(o[g][2][i], (lane & 48) | 8, 64);
#pragma unroll
        for (int g = 0; g < 2; g++)
#pragma unroll
            for (int t2 = 0; t2 < 3; t2++) {
                int c = 16 * t2 + l15;
                if (c < DH) {
#pragma unroll
                    for (int i = 0; i < 4; i++) {
                        size_t row = (size_t)(b * SPATIAL + q0 + 32 * wave + 16 * g + 4 * quad + i);
                        Og[row * DIM + h * DH + c] = f2bf(o[g][t2][i] * inv[g][i]);
                    }
                }
            }
    } else {
#pragma unroll
        for (int g = 0; g < 2; g++) {
#pragma unroll
            for (int t2 = 0; t2 < 3; t2++) {
                int c = 16 * t2 + l15;
                if (c < DH) {
#pragma unroll
                    for (int i = 0; i < 4; i++) {
                        size_t row = (size_t)(b * SPATIAL + q0 + 32 * wave + 16 * g + 4 * quad + i);
                        Opart[((size_t)kp * ROWS + row) * DIM + h * DH + c] = o[g][t2][i];
                    }
                }
            }
            if (l15 == 8) {
#pragma unroll
                for (int i = 0; i < 4; i++) {
                    size_t row = (size_t)(b * SPATIAL + q0 + 32 * wave + 16 * g + 4 * quad + i);
                    Lpart[((size_t)kp * ROWS + row) * NHEADS + h] = o[g][2][i];
                }
            }
        }
    }
}

// merge split-K partials: out = (o0+o1)/(l0+l1)
__global__ __launch_bounds__(320) void attn_merge_kernel(
    const float* __restrict__ Op, const float* __restrict__ Lp,
    ushort_t* __restrict__ Og)
{
    int row = blockIdx.x, c = threadIdx.x;
    int h = c / DH;
    float l = Lp[(size_t)row * NHEADS + h] + Lp[((size_t)ROWS + row) * NHEADS + h];
    float o = Op[(size_t)row * DIM + c] + Op[((size_t)ROWS + row) * DIM + c];
    Og[(size_t)row * DIM + c] = f2bf(o / l);
}

// ---------------------------------------------------------------------------
extern "C" void kernel_launch(void* const* d_in, const int* in_sizes, int n_in,
                              void* d_out, int out_size, void* d_ws, size_t ws_size,
                              hipStream_t stream) {
    (void)in_sizes; (void)n_in; (void)out_size; (void)ws_size;
    const float* q      = (const float*)d_in[0];
    const float* kv     = (const float*)d_in[1];
    const float* gn_s   = (const float*)d_in[2];
    const float* gn_b   = (const float*)d_in[3];
    const float* cin_w  = (const float*)d_in[4];
    const float* cin_b  = (const float*)d_in[5];
    const float* ln0_s  = (const float*)d_in[6];
    const float* ln0_b  = (const float*)d_in[7];
    const float* a1_wq  = (const float*)d_in[8];
    const float* a1_wk  = (const float*)d_in[9];
    const float* a1_wv  = (const float*)d_in[10];
    const float* a1_wo  = (const float*)d_in[11];
    const float* a1_bo  = (const float*)d_in[12];
    const float* ln1_s  = (const float*)d_in[13];
    const float* ln1_b  = (const float*)d_in[14];
    const float* a2_wq  = (const float*)d_in[15];
    const float* a2_wk  = (const float*)d_in[16];
    const float* a2_wv  = (const float*)d_in[17];
    const float* a2_wo  = (const float*)d_in[18];
    const float* a2_bo  = (const float*)d_in[19];
    const float* lnA_s  = (const float*)d_in[20];
    const float* lnA_b  = (const float*)d_in[21];
    const float* fc0_w  = (const float*)d_in[22];
    const float* fc0_b  = (const float*)d_in[23];
    const float* fc1_w  = (const float*)d_in[24];
    const float* fc1_b  = (const float*)d_in[25];
    const float* cout_w = (const float*)d_in[26];
    const float* cout_b = (const float*)d_in[27];
    float* out = (float*)d_out;

    // ---- workspace carve ----
    char* p = (char*)d_ws;
    auto carve = [&](size_t bytes) -> char* {
        char* r = p;
        p += (bytes + 255) & ~(size_t)255;
        return r;
    };
    float*    stats  = (float*)carve(512);
    float*    B0     = (float*)carve((size_t)ROWS * DIM * 4);
    float*    B2     = (float*)carve((size_t)ROWS * DIM * 4);
    ushort_t* gnO    = (ushort_t*)carve((size_t)ROWS * DIM * 2);
    ushort_t* ln0O   = (ushort_t*)carve((size_t)ROWS * DIM * 2);
    ushort_t* QKV    = (ushort_t*)carve((size_t)ROWS * 960 * 2);
    ushort_t* attnO  = (ushort_t*)carve((size_t)ROWS * DIM * 2);
    ushort_t* ln1O   = (ushort_t*)carve((size_t)ROWS * DIM * 2);
    ushort_t* Q2     = (ushort_t*)carve((size_t)ROWS * DIM * 2);
    ushort_t* KVc    = (ushort_t*)carve((size_t)BATCH * KVL * 640 * 2);
    ushort_t* lnAO   = (ushort_t*)carve((size_t)ROWS * DIM * 2);
    ushort_t* GLU    = (ushort_t*)carve((size_t)ROWS * FF * 2);
    ushort_t* X2     = (ushort_t*)carve((size_t)ROWS * DIM * 2);
    ushort_t* kvbf   = (ushort_t*)carve((size_t)BATCH * KVL * KVD * 2);
    ushort_t* qkv_t  = (ushort_t*)carve((size_t)960 * 320 * 2);
    ushort_t* cin_t  = (ushort_t*)carve((size_t)320 * 320 * 2);
    ushort_t* a1wo_t = (ushort_t*)carve((size_t)320 * 320 * 2);
    ushort_t* a2wq_t = (ushort_t*)carve((size_t)320 * 320 * 2);
    ushort_t* kvx_t  = (ushort_t*)carve((size_t)640 * 768 * 2);
    ushort_t* a2wo_t = (ushort_t*)carve((size_t)320 * 320 * 2);
    ushort_t* fc0_t  = (ushort_t*)carve((size_t)2560 * 320 * 2);
    ushort_t* fc1_t  = (ushort_t*)carve((size_t)320 * 1280 * 2);
    ushort_t* cout_t = (ushort_t*)carve((size_t)320 * 320 * 2);
    // split-K partials alias dead/late buffers (GLU used only in FFN phase;
    // gnO dead after conv_in)
    float* Opart = (float*)GLU;    // 2 * ROWS * DIM f32 = 21.0 MB == GLU size
    float* Lpart = (float*)gnO;    // 2 * ROWS * 8 f32 = 0.5 MB

    auto gemm = [&](const ushort_t* A, const ushort_t* Wt, const float* bias,
                    const float* resid, float* Cf, ushort_t* Cb,
                    int M, int N, int K, float qsc = 1.f, int ncut = 0) {
        gemm128_kernel<<<dim3(M / 128, N / 64), 256, 0, stream>>>(
            A, Wt, bias, resid, Cf, Cb, M, N, K, qsc, ncut);
    };

    // ---- fused weight prep ----
    {
        WTab tab;
        int t0 = 0;
        auto seg = [&](int i, const float* s, ushort_t* d, int K, int N) {
            tab.s[i] = {s, d, K, N, t0};
            t0 += (K / 32) * (N / 32);
        };
        seg(0,  cin_w,  cin_t,             320, 320);
        seg(1,  a1_wq,  qkv_t,             320, 320);
        seg(2,  a1_wk,  qkv_t + 320 * 320, 320, 320);
        seg(3,  a1_wv,  qkv_t + 640 * 320, 320, 320);
        seg(4,  a1_wo,  a1wo_t,            320, 320);
        seg(5,  a2_wq,  a2wq_t,            320, 320);
        seg(6,  a2_wk,  kvx_t,             768, 320);
        seg(7,  a2_wv,  kvx_t + 320 * 768, 768, 320);
        seg(8,  a2_wo,  a2wo_t,            320, 320);
        seg(9,  fc0_w,  fc0_t,             320, 2560);
        seg(10, fc1_w,  fc1_t,             1280, 320);
        seg(11, cout_w, cout_t,            320, 320);
        wtrans_all_kernel<<<t0, 256, 0, stream>>>(tab);
    }
    {
        int n = BATCH * KVL * KVD;
        cvt_bf16_kernel<<<(n + 255) / 256, 256, 0, stream>>>(kv, kvbf, n);
    }

    // ---- GroupNorm + conv_in ----
    zero_stats_kernel<<<1, 128, 0, stream>>>(stats);
    gn_partial_kernel<<<dim3(16, 64), 256, 0, stream>>>(q, stats);
    gn_apply_transpose_kernel<<<dim3(SPATIAL / 32, DIM / 32, BATCH), dim3(32, 32), 0, stream>>>(
        q, stats, gn_s, gn_b, gnO);
    gemm(gnO, cin_t, cin_b, nullptr, B0, nullptr, ROWS, DIM, DIM);

    // ---- self-attention (split-K flash) ----
    ln_kernel<<<ROWS, 64, 0, stream>>>(B0, ln0_s, ln0_b, ln0O);
    gemm(ln0O, qkv_t, nullptr, nullptr, nullptr, QKV, ROWS, 960, DIM, QK_EXP2_SCALE, 320);
    flash_kernel<2><<<dim3(SPATIAL / TQ, NHEADS, BATCH * 2), 256, 0, stream>>>(
        QKV, QKV + 320, QKV + 640, nullptr, Opart, Lpart, 960, 960, SPATIAL);
    attn_merge_kernel<<<ROWS, 320, 0, stream>>>(Opart, Lpart, attnO);
    gemm(attnO, a1wo_t, a1_bo, B0, B0, nullptr, ROWS, DIM, DIM);

    // ---- cross-attention ----
    ln_kernel<<<ROWS, 64, 0, stream>>>(B0, ln1_s, ln1_b, ln1O);
    gemm(ln1O, a2wq_t, nullptr, nullptr, nullptr, Q2, ROWS, DIM, DIM, QK_EXP2_SCALE, 320);
    gemm_small_kernel<<<dim3(3, 10), 256, 0, stream>>>(kvbf, kvx_t, KVc, BATCH * KVL, 640, KVD);
    flash_kernel<1><<<dim3(SPATIAL / TQ, NHEADS, BATCH), 256, 0, stream>>>(
        Q2, KVc, KVc + 320, attnO, nullptr, nullptr, 320, 640, KVL);
    gemm(attnO, a2wo_t, a2_bo, B0, B0, nullptr, ROWS, DIM, DIM);

    // ---- FFN (GEGLU) ----
    ln_kernel<<<ROWS, 64, 0, stream>>>(B0, lnA_s, lnA_b, lnAO);
    geglu128_kernel<<<dim3(ROWS / 128, FF / 64), 256, 0, stream>>>(lnAO, fc0_t, fc0_b, GLU, ROWS);
    gemm(GLU, fc1_t, fc1_b, B0, nullptr, X2, ROWS, DIM, FF);

    // ---- conv_out + res1 ----
    gemm(X2, cout_t, cout_b, nullptr, B2, nullptr, ROWS, DIM, DIM);
    out_transpose_kernel<<<dim3(SPATIAL / 32, DIM / 32, BATCH), dim3(32, 32), 0, stream>>>(B2, q, out);
}